// Round 2
// baseline (2698.209 us; speedup 1.0000x reference)
//
#include <hip/hip_runtime.h>
#include <hip/hip_bf16.h>

#define S_LEN 4096
#define D_DIM 512
#define H_NUM 8
#define DK_DIM 64
#define FF_DIM 2048

// ---------------------------------------------------------------------------
// LayerNorm: one block per row. Matches reference: population var * D/(D-1)
// (Bessel / torch.std), eps added to STD (not var), scalar alpha/beta.
// ---------------------------------------------------------------------------
__global__ __launch_bounds__(256) void ln_kernel(
    const float* __restrict__ x,
    const float* __restrict__ aP, const float* __restrict__ bP,
    float* __restrict__ out)
{
    const int row = blockIdx.x;
    const int tid = threadIdx.x;
    float vals[2];
#pragma unroll
    for (int i = 0; i < 2; ++i) {
        int d = tid + i * 256;
        vals[i] = x[(size_t)row * D_DIM + d];
    }
    float sum = vals[0] + vals[1];
    float sq  = vals[0] * vals[0] + vals[1] * vals[1];
#pragma unroll
    for (int off = 1; off < 64; off <<= 1) {
        sum += __shfl_xor(sum, off);
        sq  += __shfl_xor(sq, off);
    }
    __shared__ float ssum[4], ssq[4];
    int wid = tid >> 6;
    if ((tid & 63) == 0) { ssum[wid] = sum; ssq[wid] = sq; }
    __syncthreads();
    sum = ssum[0] + ssum[1] + ssum[2] + ssum[3];
    sq  = ssq[0] + ssq[1] + ssq[2] + ssq[3];
    float mean = sum * (1.0f / D_DIM);
    float var  = (sq - (float)D_DIM * mean * mean) * (1.0f / (D_DIM - 1));
    var = fmaxf(var, 0.0f);
    float stdv = sqrtf(var);
    float scale = aP[0] / (stdv + 1e-6f);
    float beta  = bP[0];
#pragma unroll
    for (int i = 0; i < 2; ++i) {
        int d = tid + i * 256;
        out[(size_t)row * D_DIM + d] = (vals[i] - mean) * scale + beta;
    }
}

// ---------------------------------------------------------------------------
// Generic fp32 SIMT GEMM: C = A(MxK) @ B(KxN) + bias(N)
// epilogue: optional relu, optional fp32 residual. 64x64 tile, 256 threads,
// 4x4 accumulator per thread.
// ---------------------------------------------------------------------------
#define BM 64
#define BN 64
#define BKK 16
__global__ __launch_bounds__(256) void gemm_f32(
    const float* __restrict__ A, const float* __restrict__ B,
    const float* __restrict__ bias,
    const float* __restrict__ res,
    float* __restrict__ outF,
    int M, int N, int K, int do_relu)
{
    __shared__ float As[BKK][BM];
    __shared__ float Bs[BKK][BN + 1];
    const int bm = blockIdx.y * BM;
    const int bn = blockIdx.x * BN;
    const int tid = threadIdx.x;
    const int tr = tid / 16;   // 0..15
    const int tc = tid % 16;   // 0..15
    float acc[4][4] = {};

    for (int k0 = 0; k0 < K; k0 += BKK) {
        for (int i = tid; i < BM * BKK; i += 256) {
            int m = i / BKK, kk = i % BKK;
            As[kk][m] = A[(size_t)(bm + m) * K + k0 + kk];
        }
        for (int i = tid; i < BKK * BN; i += 256) {
            int kk = i / BN, n = i % BN;
            Bs[kk][n] = B[(size_t)(k0 + kk) * N + bn + n];
        }
        __syncthreads();
#pragma unroll
        for (int kk = 0; kk < BKK; ++kk) {
            float a[4], b[4];
#pragma unroll
            for (int i = 0; i < 4; ++i) a[i] = As[kk][tr * 4 + i];
#pragma unroll
            for (int j = 0; j < 4; ++j) b[j] = Bs[kk][tc * 4 + j];
#pragma unroll
            for (int i = 0; i < 4; ++i)
#pragma unroll
                for (int j = 0; j < 4; ++j)
                    acc[i][j] = fmaf(a[i], b[j], acc[i][j]);
        }
        __syncthreads();
    }

#pragma unroll
    for (int i = 0; i < 4; ++i) {
        int m = bm + tr * 4 + i;
#pragma unroll
        for (int j = 0; j < 4; ++j) {
            int n = bn + tc * 4 + j;
            float v = acc[i][j] + bias[n];
            if (do_relu) v = fmaxf(v, 0.0f);
            size_t idx = (size_t)m * N + n;
            if (res) v += res[idx];
            outF[idx] = v;
        }
    }
}

// ---------------------------------------------------------------------------
// Flash attention (fp32): one block = 32 q-rows of one head. 256 threads
// arranged (32 rows) x (8 col-groups). Online softmax, K/V tiles of 64.
// q,k,v,o are [S][D] fp32 with head h at columns h*64..h*64+63.
// ---------------------------------------------------------------------------
#define BQ 32
#define BKT 64
__global__ __launch_bounds__(256) void flash_attn(
    const float* __restrict__ q, const float* __restrict__ k,
    const float* __restrict__ v, const int* __restrict__ mask,
    float* __restrict__ o)
{
    const int head = blockIdx.y;
    const int q0 = blockIdx.x * BQ;
    const int tid = threadIdx.x;
    const int r  = tid >> 3;  // 0..31 q-row within tile
    const int cg = tid & 7;   // 0..7 col-group

    __shared__ float Qt[BQ][DK_DIM + 1];    // [row][d]
    __shared__ float Kt[DK_DIM][BKT + 1];   // transposed: [d][key]
    __shared__ float Vt[BKT][DK_DIM + 1];   // [key][d]
    __shared__ float Pt[BQ][BKT + 1];       // probs

    const size_t ld = D_DIM;
    const int hoff = head * DK_DIM;

    for (int i = tid; i < BQ * DK_DIM; i += 256) {
        int rr = i >> 6, d = i & 63;
        Qt[rr][d] = q[(size_t)(q0 + rr) * ld + hoff + d];
    }

    float O[8] = {};
    float m = -1e30f, l = 0.0f;

    for (int kt = 0; kt < S_LEN; kt += BKT) {
        __syncthreads();   // protect Kt/Vt (and Qt on iter 0) from prior readers
        for (int i = tid; i < BKT * DK_DIM; i += 256) {
            int c = i >> 6, d = i & 63;
            Kt[d][c] = k[(size_t)(kt + c) * ld + hoff + d];
            Vt[c][d] = v[(size_t)(kt + c) * ld + hoff + d];
        }
        __syncthreads();

        // scores for this thread's 8 key columns
        float s[8] = {};
#pragma unroll 8
        for (int d = 0; d < DK_DIM; ++d) {
            float qd = Qt[r][d];
#pragma unroll
            for (int jj = 0; jj < 8; ++jj)
                s[jj] = fmaf(qd, Kt[d][cg * 8 + jj], s[jj]);
        }
        float tmax = -1e30f;
#pragma unroll
        for (int jj = 0; jj < 8; ++jj) {
            s[jj] *= 0.125f;  // 1/sqrt(64)
            if (mask[kt + cg * 8 + jj] == 0) s[jj] = -1e9f;
            tmax = fmaxf(tmax, s[jj]);
        }
#pragma unroll
        for (int off = 1; off < 8; off <<= 1)
            tmax = fmaxf(tmax, __shfl_xor(tmax, off));
        float mnew = fmaxf(m, tmax);
        float alpha = __expf(m - mnew);
        float psum = 0.0f;
#pragma unroll
        for (int jj = 0; jj < 8; ++jj) {
            float p = __expf(s[jj] - mnew);
            Pt[r][cg * 8 + jj] = p;
            psum += p;
        }
#pragma unroll
        for (int off = 1; off < 8; off <<= 1)
            psum += __shfl_xor(psum, off);
        l = l * alpha + psum;
        m = mnew;
#pragma unroll
        for (int j = 0; j < 8; ++j) O[j] *= alpha;

        // P @ V  (Pt[r][*] written by row r's 8 threads — same wave, and the
        // loop-top __syncthreads separates iterations)
#pragma unroll 8
        for (int c = 0; c < BKT; ++c) {
            float p = Pt[r][c];
#pragma unroll
            for (int j = 0; j < 8; ++j)
                O[j] = fmaf(p, Vt[c][cg * 8 + j], O[j]);
        }
    }

    float inv = 1.0f / l;
#pragma unroll
    for (int j = 0; j < 8; ++j)
        o[(size_t)(q0 + r) * ld + hoff + cg * 8 + j] = O[j] * inv;
}

// ---------------------------------------------------------------------------
extern "C" void kernel_launch(void* const* d_in, const int* in_sizes, int n_in,
                              void* d_out, int out_size, void* d_ws, size_t ws_size,
                              hipStream_t stream) {
    (void)in_sizes; (void)n_in; (void)out_size; (void)ws_size;
    const float* x    = (const float*)d_in[0];
    const int*   mask = (const int*)d_in[1];
    const float* wq = (const float*)d_in[2];
    const float* bq = (const float*)d_in[3];
    const float* wk = (const float*)d_in[4];
    const float* bk = (const float*)d_in[5];
    const float* wv = (const float*)d_in[6];
    const float* bv = (const float*)d_in[7];
    const float* wo = (const float*)d_in[8];
    const float* bo = (const float*)d_in[9];
    const float* w1 = (const float*)d_in[10];
    const float* b1 = (const float*)d_in[11];
    const float* w2 = (const float*)d_in[12];
    const float* b2 = (const float*)d_in[13];
    const float* ln1a = (const float*)d_in[14];
    const float* ln1b = (const float*)d_in[15];
    const float* ln2a = (const float*)d_in[16];
    const float* ln2b = (const float*)d_in[17];
    float* out = (float*)d_out;

    const size_t SD = (size_t)S_LEN * D_DIM;   // 2M floats
    float* ws   = (float*)d_ws;
    // Buffer reuse to keep ws usage at 7*SD*4 = 56 MB:
    float* h    = ws;            // buf0: LN1 out
    float* qb   = ws + 1 * SD;   // buf1
    float* kb   = ws + 2 * SD;   // buf2
    float* vb   = ws + 3 * SD;   // buf3
    float* attn = ws;            // buf0 (h dead after v-gemm)
    float* x2   = ws + 1 * SD;   // buf1 (qb dead after flash)
    float* h2   = ws + 2 * SD;   // buf2 (kb dead after flash)
    float* ff1  = ws + 3 * SD;   // buf3..buf6, 4*SD (vb dead after flash)

    dim3 blk(256);

    // LN1
    ln_kernel<<<dim3(S_LEN), blk, 0, stream>>>(x, ln1a, ln1b, h);

    // QKV projections
    dim3 gD(D_DIM / BN, S_LEN / BM);
    gemm_f32<<<gD, blk, 0, stream>>>(h, wq, bq, nullptr, qb,
                                     S_LEN, D_DIM, D_DIM, 0);
    gemm_f32<<<gD, blk, 0, stream>>>(h, wk, bk, nullptr, kb,
                                     S_LEN, D_DIM, D_DIM, 0);
    gemm_f32<<<gD, blk, 0, stream>>>(h, wv, bv, nullptr, vb,
                                     S_LEN, D_DIM, D_DIM, 0);

    // attention (reads qb,kb,vb; writes attn=buf0)
    flash_attn<<<dim3(S_LEN / BQ, H_NUM), blk, 0, stream>>>(qb, kb, vb, mask, attn);

    // output projection + residual(x) -> x2 (buf1)
    gemm_f32<<<gD, blk, 0, stream>>>(attn, wo, bo, x, x2,
                                     S_LEN, D_DIM, D_DIM, 0);

    // LN2 -> h2 (buf2)
    ln_kernel<<<dim3(S_LEN), blk, 0, stream>>>(x2, ln2a, ln2b, h2);

    // FFN
    dim3 gF(FF_DIM / BN, S_LEN / BM);
    gemm_f32<<<gF, blk, 0, stream>>>(h2, w1, b1, nullptr, ff1,
                                     S_LEN, FF_DIM, D_DIM, 1);
    gemm_f32<<<gD, blk, 0, stream>>>(ff1, w2, b2, x2, out,
                                     S_LEN, D_DIM, FF_DIM, 0);
}

// Round 3
// 394.030 us; speedup vs baseline: 6.8477x; 6.8477x over previous
//
#include <hip/hip_runtime.h>
#include <hip/hip_bf16.h>

#define S_LEN 4096
#define D_DIM 512
#define H_NUM 8
#define DK_DIM 64
#define FF_DIM 2048

typedef __attribute__((ext_vector_type(8))) short short8;
typedef __attribute__((ext_vector_type(4))) float f32x4;

__device__ __forceinline__ ushort f2bf(float f) {
    union { float f; uint u; } v; v.f = f;
    uint r = v.u + 0x7FFF + ((v.u >> 16) & 1);
    return (ushort)(r >> 16);
}

__device__ __forceinline__ void gload_lds16(const void* g, void* l) {
    __builtin_amdgcn_global_load_lds(
        (const __attribute__((address_space(1))) void*)g,
        (__attribute__((address_space(3))) void*)l,
        16, 0, 0);
}

// ---------------------------------------------------------------------------
// Tiled transpose + fp32->bf16 cast: src fp32 [K][N] -> dst bf16 [N][K]
// ---------------------------------------------------------------------------
__global__ __launch_bounds__(256) void transpose_cast(
    const float* __restrict__ src, ushort* __restrict__ dst, int K, int N)
{
    __shared__ float t[32][33];
    int tx = threadIdx.x & 31, ty = threadIdx.x >> 5;   // 32 x 8
    int gn = blockIdx.x * 32, gk = blockIdx.y * 32;
#pragma unroll
    for (int i = 0; i < 32; i += 8)
        t[ty + i][tx] = src[(size_t)(gk + ty + i) * N + gn + tx];
    __syncthreads();
#pragma unroll
    for (int i = 0; i < 32; i += 8)
        dst[(size_t)(gn + ty + i) * K + gk + tx] = f2bf(t[tx][ty + i]);
}

// ---------------------------------------------------------------------------
// LayerNorm: fp32 in -> bf16 out. Bessel var (torch.std), eps added to std.
// ---------------------------------------------------------------------------
__global__ __launch_bounds__(256) void ln_kernel(
    const float* __restrict__ x,
    const float* __restrict__ aP, const float* __restrict__ bP,
    ushort* __restrict__ out)
{
    const int row = blockIdx.x;
    const int tid = threadIdx.x;
    float vals[2];
#pragma unroll
    for (int i = 0; i < 2; ++i)
        vals[i] = x[(size_t)row * D_DIM + tid + i * 256];
    float sum = vals[0] + vals[1];
    float sq  = vals[0] * vals[0] + vals[1] * vals[1];
#pragma unroll
    for (int off = 1; off < 64; off <<= 1) {
        sum += __shfl_xor(sum, off);
        sq  += __shfl_xor(sq, off);
    }
    __shared__ float ssum[4], ssq[4];
    int wid = tid >> 6;
    if ((tid & 63) == 0) { ssum[wid] = sum; ssq[wid] = sq; }
    __syncthreads();
    sum = ssum[0] + ssum[1] + ssum[2] + ssum[3];
    sq  = ssq[0] + ssq[1] + ssq[2] + ssq[3];
    float mean = sum * (1.0f / D_DIM);
    float var  = (sq - (float)D_DIM * mean * mean) * (1.0f / (D_DIM - 1));
    var = fmaxf(var, 0.0f);
    float scale = aP[0] / (sqrtf(var) + 1e-6f);
    float beta  = bP[0];
#pragma unroll
    for (int i = 0; i < 2; ++i)
        out[(size_t)row * D_DIM + tid + i * 256] =
            f2bf((vals[i] - mean) * scale + beta);
}

// ---------------------------------------------------------------------------
// MFMA bf16 GEMM: C = A[M][K](bf16) @ Bt[N][K](bf16)^T + bias(fp32)
// 128x64 tile, BK=64 (two 32-k LDS panels), 256 threads = 4 waves,
// wave = 32 rows x 64 cols = 2x4 grid of 16x16x32 MFMAs.
// global_load_lds width-16 staging; epilogue relu / fp32-res / f32-or-bf16 out.
// ---------------------------------------------------------------------------
__global__ __launch_bounds__(256) void gemm_mfma(
    const ushort* __restrict__ A, const ushort* __restrict__ Bt,
    const float* __restrict__ bias, const float* __restrict__ res,
    float* __restrict__ outF, ushort* __restrict__ outB,
    int M, int N, int K, int relu)
{
    __shared__ ushort As[2][128][32];   // [panel][m][k%32]  16 KB
    __shared__ ushort Bs[2][64][32];    // [panel][n][k%32]   8 KB
    const int tid = threadIdx.x;
    const int w = tid >> 6, lane = tid & 63;
    const int l15 = lane & 15, quad = lane >> 4;
    const int m0 = blockIdx.y * 128, n0 = blockIdx.x * 64;

    f32x4 acc[2][4] = {};

    // staging addresses: wave w stages A rows 32w..32w+31, B rows 16w..16w+15
    const char* gA  = (const char*)(A  + (size_t)(m0 + 32 * w + lane / 4) * K) + (lane % 4) * 16;
    const char* gA2 = gA + (size_t)16 * K * 2;
    const char* gB  = (const char*)(Bt + (size_t)(n0 + 16 * w + lane / 4) * K) + (lane % 4) * 16;

    for (int k0 = 0; k0 < K; k0 += 64) {
        __syncthreads();
        gload_lds16(gA,       &As[0][32 * w][0]);
        gload_lds16(gA + 64,  &As[1][32 * w][0]);
        gload_lds16(gA2,      &As[0][32 * w + 16][0]);
        gload_lds16(gA2 + 64, &As[1][32 * w + 16][0]);
        gload_lds16(gB,       &Bs[0][16 * w][0]);
        gload_lds16(gB + 64,  &Bs[1][16 * w][0]);
        gA += 128; gA2 += 128; gB += 128;
        __syncthreads();
#pragma unroll
        for (int ks = 0; ks < 2; ++ks) {
            short8 a0 = *(const short8*)&As[ks][32 * w + l15][quad * 8];
            short8 a1 = *(const short8*)&As[ks][32 * w + 16 + l15][quad * 8];
            short8 b0 = *(const short8*)&Bs[ks][0 * 16 + l15][quad * 8];
            short8 b1 = *(const short8*)&Bs[ks][1 * 16 + l15][quad * 8];
            short8 b2 = *(const short8*)&Bs[ks][2 * 16 + l15][quad * 8];
            short8 b3 = *(const short8*)&Bs[ks][3 * 16 + l15][quad * 8];
            acc[0][0] = __builtin_amdgcn_mfma_f32_16x16x32_bf16(a0, b0, acc[0][0], 0, 0, 0);
            acc[0][1] = __builtin_amdgcn_mfma_f32_16x16x32_bf16(a0, b1, acc[0][1], 0, 0, 0);
            acc[0][2] = __builtin_amdgcn_mfma_f32_16x16x32_bf16(a0, b2, acc[0][2], 0, 0, 0);
            acc[0][3] = __builtin_amdgcn_mfma_f32_16x16x32_bf16(a0, b3, acc[0][3], 0, 0, 0);
            acc[1][0] = __builtin_amdgcn_mfma_f32_16x16x32_bf16(a1, b0, acc[1][0], 0, 0, 0);
            acc[1][1] = __builtin_amdgcn_mfma_f32_16x16x32_bf16(a1, b1, acc[1][1], 0, 0, 0);
            acc[1][2] = __builtin_amdgcn_mfma_f32_16x16x32_bf16(a1, b2, acc[1][2], 0, 0, 0);
            acc[1][3] = __builtin_amdgcn_mfma_f32_16x16x32_bf16(a1, b3, acc[1][3], 0, 0, 0);
        }
    }

#pragma unroll
    for (int mt = 0; mt < 2; ++mt) {
#pragma unroll
        for (int nt = 0; nt < 4; ++nt) {
#pragma unroll
            for (int r = 0; r < 4; ++r) {
                int mm = m0 + 32 * w + mt * 16 + quad * 4 + r;
                int nn = n0 + nt * 16 + l15;
                float v = acc[mt][nt][r] + bias[nn];
                if (relu) v = fmaxf(v, 0.0f);
                size_t idx = (size_t)mm * N + nn;
                if (res) v += res[idx];
                if (outF) outF[idx] = v;
                else      outB[idx] = f2bf(v);
            }
        }
    }
}

// ---------------------------------------------------------------------------
// MFMA bf16 flash attention. Block = 64 q-rows x 1 head, 4 waves x 16 rows.
// Q/K staged via global_load_lds into [panel][row][32] layouts; V transposed
// to Vt[panel][dk][key%32]; P round-trips through per-wave LDS. Online
// softmax in-register via 16-lane shfl reductions.
// q,k,v,o are bf16 [S][512], head h at cols h*64..h*64+63.
// ---------------------------------------------------------------------------
__global__ __launch_bounds__(256) void flash_mfma(
    const ushort* __restrict__ q, const ushort* __restrict__ k,
    const ushort* __restrict__ v, const int* __restrict__ mask,
    ushort* __restrict__ o)
{
    __shared__ ushort Qs[2][64][32];      // 8 KB   [ks][qrow][dk%32]
    __shared__ ushort Ks[2][64][32];      // 8 KB   [ks][key][dk%32]
    __shared__ ushort Vt[2][64][32];      // 8 KB   [ks][dk][key%32]
    __shared__ ushort Ps[4][2][16][32];   // 8 KB   [wave][ks][qrow][key%32]

    const int head = blockIdx.y;
    const int q0 = blockIdx.x * 64;
    const int tid = threadIdx.x;
    const int w = tid >> 6, lane = tid & 63;
    const int l15 = lane & 15, quad = lane >> 4;
    const int hoff = head * DK_DIM;

    // ---- stage Q once: wave w stages its own 16 rows, both 32-dk panels
    {
        const char* gq = (const char*)(q + (size_t)(q0 + 16 * w + lane / 4) * D_DIM + hoff)
                         + (lane % 4) * 16;
        gload_lds16(gq,      &Qs[0][16 * w][0]);
        gload_lds16(gq + 64, &Qs[1][16 * w][0]);
    }

    const char* gk = (const char*)(k + (size_t)(16 * w + lane / 4) * D_DIM + hoff)
                     + (lane % 4) * 16;

    f32x4 oacc[4] = {};
    float mrow[4], lrow[4];
#pragma unroll
    for (int r = 0; r < 4; ++r) { mrow[r] = -1e30f; lrow[r] = 0.0f; }

    for (int kt = 0; kt < S_LEN; kt += 64) {
        __syncthreads();   // prior-iter LDS readers done (also covers Q gll on iter 0)
        // stage K tile (gll): wave w rows kt+16w..+15, both panels
        gload_lds16(gk,      &Ks[0][16 * w][0]);
        gload_lds16(gk + 64, &Ks[1][16 * w][0]);
        gk += (size_t)64 * D_DIM * 2;
        // stage V transposed: thread -> key = tid&63, dk chunk = (tid>>6)*16
        {
            int key = tid & 63, dh = (tid >> 6) * 16;
            const ushort* gv = v + (size_t)(kt + key) * D_DIM + hoff + dh;
            short8 v0 = *(const short8*)gv;
            short8 v1 = *(const short8*)(gv + 8);
            int ks = key >> 5, k2 = key & 31;
#pragma unroll
            for (int j = 0; j < 8; ++j) Vt[ks][dh + j][k2] = (ushort)v0[j];
#pragma unroll
            for (int j = 0; j < 8; ++j) Vt[ks][dh + 8 + j][k2] = (ushort)v1[j];
        }
        __syncthreads();

        // ---- S = Q @ K^T (pre-scale applied after)
        f32x4 sacc[4] = {};
#pragma unroll
        for (int ks = 0; ks < 2; ++ks) {
            short8 aq = *(const short8*)&Qs[ks][16 * w + l15][quad * 8];
#pragma unroll
            for (int nt = 0; nt < 4; ++nt) {
                short8 bk = *(const short8*)&Ks[ks][nt * 16 + l15][quad * 8];
                sacc[nt] = __builtin_amdgcn_mfma_f32_16x16x32_bf16(aq, bk, sacc[nt], 0, 0, 0);
            }
        }

        // ---- masked, scaled online softmax (C-layout: col=l15, row=quad*4+r)
        int mv[4];
#pragma unroll
        for (int nt = 0; nt < 4; ++nt) mv[nt] = mask[kt + nt * 16 + l15];
        float rmax[4] = {-1e30f, -1e30f, -1e30f, -1e30f};
#pragma unroll
        for (int nt = 0; nt < 4; ++nt)
#pragma unroll
            for (int r = 0; r < 4; ++r) {
                float s = sacc[nt][r] * 0.125f;            // 1/sqrt(64)
                if (mv[nt] == 0) s = -1e9f;
                sacc[nt][r] = s;
                rmax[r] = fmaxf(rmax[r], s);
            }
#pragma unroll
        for (int r = 0; r < 4; ++r) {
            rmax[r] = fmaxf(rmax[r], __shfl_xor(rmax[r], 1));
            rmax[r] = fmaxf(rmax[r], __shfl_xor(rmax[r], 2));
            rmax[r] = fmaxf(rmax[r], __shfl_xor(rmax[r], 4));
            rmax[r] = fmaxf(rmax[r], __shfl_xor(rmax[r], 8));
        }
        float alpha[4], rsum[4];
#pragma unroll
        for (int r = 0; r < 4; ++r) {
            float mnew = fmaxf(mrow[r], rmax[r]);
            alpha[r] = __expf(mrow[r] - mnew);
            mrow[r] = mnew;
            rsum[r] = 0.0f;
        }
#pragma unroll
        for (int nt = 0; nt < 4; ++nt)
#pragma unroll
            for (int r = 0; r < 4; ++r) {
                float p = __expf(sacc[nt][r] - mrow[r]);
                rsum[r] += p;
                Ps[w][nt >> 1][quad * 4 + r][(nt & 1) * 16 + l15] = f2bf(p);
            }
#pragma unroll
        for (int r = 0; r < 4; ++r) {
            rsum[r] += __shfl_xor(rsum[r], 1);
            rsum[r] += __shfl_xor(rsum[r], 2);
            rsum[r] += __shfl_xor(rsum[r], 4);
            rsum[r] += __shfl_xor(rsum[r], 8);
            lrow[r] = lrow[r] * alpha[r] + rsum[r];
        }
        // rescale O accumulators
#pragma unroll
        for (int vt = 0; vt < 4; ++vt)
#pragma unroll
            for (int r = 0; r < 4; ++r)
                oacc[vt][r] *= alpha[r];

        // ---- O += P @ V  (P from per-wave LDS, V from transposed tile)
#pragma unroll
        for (int ks = 0; ks < 2; ++ks) {
            short8 ap = *(const short8*)&Ps[w][ks][l15][quad * 8];
#pragma unroll
            for (int vt = 0; vt < 4; ++vt) {
                short8 bv = *(const short8*)&Vt[ks][vt * 16 + l15][quad * 8];
                oacc[vt] = __builtin_amdgcn_mfma_f32_16x16x32_bf16(ap, bv, oacc[vt], 0, 0, 0);
            }
        }
    }

    float inv[4];
#pragma unroll
    for (int r = 0; r < 4; ++r) inv[r] = 1.0f / lrow[r];
#pragma unroll
    for (int vt = 0; vt < 4; ++vt)
#pragma unroll
        for (int r = 0; r < 4; ++r)
            o[(size_t)(q0 + 16 * w + quad * 4 + r) * D_DIM + hoff + vt * 16 + l15] =
                f2bf(oacc[vt][r] * inv[r]);
}

// ---------------------------------------------------------------------------
extern "C" void kernel_launch(void* const* d_in, const int* in_sizes, int n_in,
                              void* d_out, int out_size, void* d_ws, size_t ws_size,
                              hipStream_t stream) {
    (void)in_sizes; (void)n_in; (void)out_size; (void)ws_size;
    const float* x    = (const float*)d_in[0];
    const int*   mask = (const int*)d_in[1];
    const float* wq = (const float*)d_in[2];
    const float* bq = (const float*)d_in[3];
    const float* wk = (const float*)d_in[4];
    const float* bk = (const float*)d_in[5];
    const float* wv = (const float*)d_in[6];
    const float* bv = (const float*)d_in[7];
    const float* wo = (const float*)d_in[8];
    const float* bo = (const float*)d_in[9];
    const float* w1 = (const float*)d_in[10];
    const float* b1 = (const float*)d_in[11];
    const float* w2 = (const float*)d_in[12];
    const float* b2 = (const float*)d_in[13];
    const float* ln1a = (const float*)d_in[14];
    const float* ln1b = (const float*)d_in[15];
    const float* ln2a = (const float*)d_in[16];
    const float* ln2b = (const float*)d_in[17];
    float* out = (float*)d_out;

    char* p = (char*)d_ws;
    ushort* wqt = (ushort*)p; p += (size_t)512 * 512 * 2;
    ushort* wkt = (ushort*)p; p += (size_t)512 * 512 * 2;
    ushort* wvt = (ushort*)p; p += (size_t)512 * 512 * 2;
    ushort* wot = (ushort*)p; p += (size_t)512 * 512 * 2;
    ushort* w1t = (ushort*)p; p += (size_t)2048 * 512 * 2;   // [FF][D]
    ushort* w2t = (ushort*)p; p += (size_t)512 * 2048 * 2;   // [D][FF]
    ushort* h_bf  = (ushort*)p; p += (size_t)4096 * 512 * 2;
    ushort* qb    = (ushort*)p; p += (size_t)4096 * 512 * 2;
    ushort* kb    = (ushort*)p; p += (size_t)4096 * 512 * 2;
    ushort* vb    = (ushort*)p; p += (size_t)4096 * 512 * 2;
    ushort* at_bf = (ushort*)p; p += (size_t)4096 * 512 * 2;
    float*  x2    = (float*)p;  p += (size_t)4096 * 512 * 4;
    ushort* h2    = (ushort*)p; p += (size_t)4096 * 512 * 2;
    ushort* ff1   = (ushort*)p; p += (size_t)4096 * 2048 * 2;

    dim3 blk(256);

    // weight transpose+cast (fp32 [K][N] -> bf16 [N][K])
    transpose_cast<<<dim3(16, 16), blk, 0, stream>>>(wq, wqt, 512, 512);
    transpose_cast<<<dim3(16, 16), blk, 0, stream>>>(wk, wkt, 512, 512);
    transpose_cast<<<dim3(16, 16), blk, 0, stream>>>(wv, wvt, 512, 512);
    transpose_cast<<<dim3(16, 16), blk, 0, stream>>>(wo, wot, 512, 512);
    transpose_cast<<<dim3(64, 16), blk, 0, stream>>>(w1, w1t, 512, 2048);
    transpose_cast<<<dim3(16, 64), blk, 0, stream>>>(w2, w2t, 2048, 512);

    // LN1
    ln_kernel<<<dim3(S_LEN), blk, 0, stream>>>(x, ln1a, ln1b, h_bf);

    // QKV projections (bf16 out)
    dim3 gD(D_DIM / 64, S_LEN / 128);
    gemm_mfma<<<gD, blk, 0, stream>>>(h_bf, wqt, bq, nullptr, nullptr, qb,
                                      S_LEN, D_DIM, D_DIM, 0);
    gemm_mfma<<<gD, blk, 0, stream>>>(h_bf, wkt, bk, nullptr, nullptr, kb,
                                      S_LEN, D_DIM, D_DIM, 0);
    gemm_mfma<<<gD, blk, 0, stream>>>(h_bf, wvt, bv, nullptr, nullptr, vb,
                                      S_LEN, D_DIM, D_DIM, 0);

    // flash attention
    flash_mfma<<<dim3(S_LEN / 64, H_NUM), blk, 0, stream>>>(qb, kb, vb, mask, at_bf);

    // output projection + residual(x) -> x2 (fp32)
    gemm_mfma<<<gD, blk, 0, stream>>>(at_bf, wot, bo, x, x2, nullptr,
                                      S_LEN, D_DIM, D_DIM, 0);

    // LN2 -> h2 (bf16)
    ln_kernel<<<dim3(S_LEN), blk, 0, stream>>>(x2, ln2a, ln2b, h2);

    // FFN
    dim3 gF(FF_DIM / 64, S_LEN / 128);
    gemm_mfma<<<gF, blk, 0, stream>>>(h2, w1t, b1, nullptr, nullptr, ff1,
                                      S_LEN, FF_DIM, D_DIM, 1);
    gemm_mfma<<<gD, blk, 0, stream>>>(ff1, w2t, b2, x2, out, nullptr,
                                      S_LEN, D_DIM, FF_DIM, 0);
}

// Round 4
// 288.742 us; speedup vs baseline: 9.3447x; 1.3646x over previous
//
#include <hip/hip_runtime.h>
#include <hip/hip_bf16.h>

#define S_LEN 4096
#define D_DIM 512
#define H_NUM 8
#define DK_DIM 64
#define FF_DIM 2048
#define QLD 1536   // fused qkv row stride

typedef __attribute__((ext_vector_type(8))) short short8;
typedef __attribute__((ext_vector_type(4))) float f32x4;
typedef __attribute__((ext_vector_type(4))) ushort us4;

#if __has_builtin(__builtin_amdgcn_exp2f)
#define EXP2F __builtin_amdgcn_exp2f
#else
#define EXP2F exp2f
#endif

__device__ __forceinline__ ushort f2bf(float f) {
    union { float f; uint u; } v; v.f = f;
    uint r = v.u + 0x7FFF + ((v.u >> 16) & 1);
    return (ushort)(r >> 16);
}

__device__ __forceinline__ void gload_lds16(const void* g, void* l) {
    __builtin_amdgcn_global_load_lds(
        (const __attribute__((address_space(1))) void*)g,
        (__attribute__((address_space(3))) void*)l,
        16, 0, 0);
}

// ---------------------------------------------------------------------------
// Tiled transpose + fp32->bf16 cast: src fp32 [K][N] -> dst bf16 [N][K]
// ---------------------------------------------------------------------------
__global__ __launch_bounds__(256) void transpose_cast(
    const float* __restrict__ src, ushort* __restrict__ dst, int K, int N)
{
    __shared__ float t[32][33];
    int tx = threadIdx.x & 31, ty = threadIdx.x >> 5;   // 32 x 8
    int gn = blockIdx.x * 32, gk = blockIdx.y * 32;
#pragma unroll
    for (int i = 0; i < 32; i += 8)
        t[ty + i][tx] = src[(size_t)(gk + ty + i) * N + gn + tx];
    __syncthreads();
#pragma unroll
    for (int i = 0; i < 32; i += 8)
        dst[(size_t)(gn + ty + i) * K + gk + tx] = f2bf(t[tx][ty + i]);
}

// ---------------------------------------------------------------------------
// Prep: concat QKV bias (fp32) + mask -> additive bias array
// ---------------------------------------------------------------------------
__global__ __launch_bounds__(256) void prep_kernel(
    const float* __restrict__ bq, const float* __restrict__ bk,
    const float* __restrict__ bv, const int* __restrict__ mask,
    float* __restrict__ bqkv, float* __restrict__ mbias)
{
    int i = blockIdx.x * 256 + threadIdx.x;   // grid 16 -> 4096
    if (i < 512)       bqkv[i] = bq[i];
    else if (i < 1024) bqkv[i] = bk[i - 512];
    else if (i < 1536) bqkv[i] = bv[i - 1024];
    mbias[i] = mask[i] ? 0.0f : -1e9f;
}

// ---------------------------------------------------------------------------
// LayerNorm: fp32 in -> bf16 out. Bessel var (torch.std), eps added to std.
// ---------------------------------------------------------------------------
__global__ __launch_bounds__(256) void ln_kernel(
    const float* __restrict__ x,
    const float* __restrict__ aP, const float* __restrict__ bP,
    ushort* __restrict__ out)
{
    const int row = blockIdx.x;
    const int tid = threadIdx.x;
    float vals[2];
#pragma unroll
    for (int i = 0; i < 2; ++i)
        vals[i] = x[(size_t)row * D_DIM + tid + i * 256];
    float sum = vals[0] + vals[1];
    float sq  = vals[0] * vals[0] + vals[1] * vals[1];
#pragma unroll
    for (int off = 1; off < 64; off <<= 1) {
        sum += __shfl_xor(sum, off);
        sq  += __shfl_xor(sq, off);
    }
    __shared__ float ssum[4], ssq[4];
    int wid = tid >> 6;
    if ((tid & 63) == 0) { ssum[wid] = sum; ssq[wid] = sq; }
    __syncthreads();
    sum = ssum[0] + ssum[1] + ssum[2] + ssum[3];
    sq  = ssq[0] + ssq[1] + ssq[2] + ssq[3];
    float mean = sum * (1.0f / D_DIM);
    float var  = (sq - (float)D_DIM * mean * mean) * (1.0f / (D_DIM - 1));
    var = fmaxf(var, 0.0f);
    float scale = aP[0] / (sqrtf(var) + 1e-6f);
    float beta  = bP[0];
#pragma unroll
    for (int i = 0; i < 2; ++i)
        out[(size_t)row * D_DIM + tid + i * 256] =
            f2bf((vals[i] - mean) * scale + beta);
}

// ---------------------------------------------------------------------------
// MFMA bf16 GEMM, double-buffered async staging.
// C = A[M][K] @ Bt[N][K]^T + bias. 128x64 tile, 4 waves, wave = 32x64.
// ksl < K => split-K partial mode: raw fp32 partial to outF + bz*M*N.
// outVT: for fused-QKV, blocks with n0>=1024 write V transposed [dk][seq].
// ---------------------------------------------------------------------------
__global__ __launch_bounds__(256) void gemm_mfma(
    const ushort* __restrict__ A, const ushort* __restrict__ Bt,
    const float* __restrict__ bias, const float* __restrict__ res,
    float* __restrict__ outF, ushort* __restrict__ outB,
    ushort* __restrict__ outVT,
    int M, int N, int K, int relu, int ksl)
{
    __shared__ ushort As[2][2][128][32];   // [buf][ks][m][k%32]  32 KB
    __shared__ ushort Bs[2][2][64][32];    // 16 KB
    const int tid = threadIdx.x;
    const int w = tid >> 6, lane = tid & 63;
    const int l15 = lane & 15, quad = lane >> 4;
    const int m0 = blockIdx.y * 128, n0 = blockIdx.x * 64;
    const int kz = blockIdx.z;
    const int kbeg = kz * ksl;

    f32x4 acc[2][4] = {};

    const char* gA  = (const char*)(A  + (size_t)(m0 + 32 * w + lane / 4) * K + kbeg) + (lane % 4) * 16;
    const char* gA2 = gA + (size_t)16 * K * 2;
    const char* gB  = (const char*)(Bt + (size_t)(n0 + 16 * w + lane / 4) * K + kbeg) + (lane % 4) * 16;

    auto stage = [&](int b) {
        gload_lds16(gA,       &As[b][0][32 * w][0]);
        gload_lds16(gA + 64,  &As[b][1][32 * w][0]);
        gload_lds16(gA2,      &As[b][0][32 * w + 16][0]);
        gload_lds16(gA2 + 64, &As[b][1][32 * w + 16][0]);
        gload_lds16(gB,       &Bs[b][0][16 * w][0]);
        gload_lds16(gB + 64,  &Bs[b][1][16 * w][0]);
        gA += 128; gA2 += 128; gB += 128;
    };

    stage(0);
    const int nit = ksl >> 6;
    for (int t = 0; t < nit; ++t) {
        __syncthreads();                 // drains buf t's async loads
        if (t + 1 < nit) stage((t + 1) & 1);   // prefetch during compute
        const int b = t & 1;
#pragma unroll
        for (int ks = 0; ks < 2; ++ks) {
            short8 a0 = *(const short8*)&As[b][ks][32 * w + l15][quad * 8];
            short8 a1 = *(const short8*)&As[b][ks][32 * w + 16 + l15][quad * 8];
            short8 b0 = *(const short8*)&Bs[b][ks][0 * 16 + l15][quad * 8];
            short8 b1 = *(const short8*)&Bs[b][ks][1 * 16 + l15][quad * 8];
            short8 b2 = *(const short8*)&Bs[b][ks][2 * 16 + l15][quad * 8];
            short8 b3 = *(const short8*)&Bs[b][ks][3 * 16 + l15][quad * 8];
            acc[0][0] = __builtin_amdgcn_mfma_f32_16x16x32_bf16(a0, b0, acc[0][0], 0, 0, 0);
            acc[0][1] = __builtin_amdgcn_mfma_f32_16x16x32_bf16(a0, b1, acc[0][1], 0, 0, 0);
            acc[0][2] = __builtin_amdgcn_mfma_f32_16x16x32_bf16(a0, b2, acc[0][2], 0, 0, 0);
            acc[0][3] = __builtin_amdgcn_mfma_f32_16x16x32_bf16(a0, b3, acc[0][3], 0, 0, 0);
            acc[1][0] = __builtin_amdgcn_mfma_f32_16x16x32_bf16(a1, b0, acc[1][0], 0, 0, 0);
            acc[1][1] = __builtin_amdgcn_mfma_f32_16x16x32_bf16(a1, b1, acc[1][1], 0, 0, 0);
            acc[1][2] = __builtin_amdgcn_mfma_f32_16x16x32_bf16(a1, b2, acc[1][2], 0, 0, 0);
            acc[1][3] = __builtin_amdgcn_mfma_f32_16x16x32_bf16(a1, b3, acc[1][3], 0, 0, 0);
        }
    }

    // ---- epilogue
    if (ksl < K) {   // split-K partial: raw accumulators
        float* of = outF + (size_t)kz * M * N;
#pragma unroll
        for (int mt = 0; mt < 2; ++mt)
#pragma unroll
            for (int nt = 0; nt < 4; ++nt)
#pragma unroll
                for (int r = 0; r < 4; ++r) {
                    int mm = m0 + 32 * w + mt * 16 + quad * 4 + r;
                    int nn = n0 + nt * 16 + l15;
                    of[(size_t)mm * N + nn] = acc[mt][nt][r];
                }
        return;
    }

    if (outVT && n0 >= 1024) {   // V columns of fused QKV: write transposed
#pragma unroll
        for (int mt = 0; mt < 2; ++mt)
#pragma unroll
            for (int nt = 0; nt < 4; ++nt) {
                int nn = n0 + nt * 16 + l15;
                int mmb = m0 + 32 * w + mt * 16 + quad * 4;
                us4 pk;
#pragma unroll
                for (int r = 0; r < 4; ++r)
                    pk[r] = (short)f2bf(acc[mt][nt][r] + bias[nn]);
                *(us4*)(outVT + (size_t)(nn - 1024) * S_LEN + mmb) = pk;
            }
        return;
    }

#pragma unroll
    for (int mt = 0; mt < 2; ++mt)
#pragma unroll
        for (int nt = 0; nt < 4; ++nt)
#pragma unroll
            for (int r = 0; r < 4; ++r) {
                int mm = m0 + 32 * w + mt * 16 + quad * 4 + r;
                int nn = n0 + nt * 16 + l15;
                float v = acc[mt][nt][r] + bias[nn];
                if (relu) v = fmaxf(v, 0.0f);
                size_t idx = (size_t)mm * N + nn;
                if (res) v += res[idx];
                if (outF) outF[idx] = v;
                else      outB[idx] = f2bf(v);
            }
}

// ---------------------------------------------------------------------------
// MFMA bf16 flash attention, no-max softmax, double-buffered K/V staging.
// q at qkv cols 0..511, k at 512..1023 (row stride 1536); V pre-transposed
// vbt [512 dk][4096 seq]. Block = 64 q-rows x 1 head, 4 waves x 16 rows.
// ---------------------------------------------------------------------------
__global__ __launch_bounds__(256) void flash_mfma(
    const ushort* __restrict__ qkv, const ushort* __restrict__ vbt,
    const float* __restrict__ mbias, ushort* __restrict__ o)
{
    __shared__ ushort Qs[2][64][32];       //  8 KB [ks][qrow][dk%32]
    __shared__ ushort Ks[2][2][64][32];    // 16 KB [buf][ks][key][dk%32]
    __shared__ ushort Vt[2][2][64][32];    // 16 KB [buf][ks][dk][key%32]
    __shared__ ushort Ps[4][2][16][32];    //  8 KB [wave][ks][qrow][key%32]

    const int head = blockIdx.y;
    const int q0 = blockIdx.x * 64;
    const int tid = threadIdx.x;
    const int w = tid >> 6, lane = tid & 63;
    const int l15 = lane & 15, quad = lane >> 4;
    const int hoff = head * DK_DIM;

    // stage Q once
    {
        const char* gq = (const char*)(qkv + (size_t)(q0 + 16 * w + lane / 4) * QLD + hoff)
                         + (lane % 4) * 16;
        gload_lds16(gq,      &Qs[0][16 * w][0]);
        gload_lds16(gq + 64, &Qs[1][16 * w][0]);
    }

    const char* gk = (const char*)(qkv + (size_t)(16 * w + lane / 4) * QLD + 512 + hoff)
                     + (lane % 4) * 16;
    const char* gv = (const char*)(vbt + (size_t)(hoff + 16 * w + lane / 4) * S_LEN)
                     + (lane % 4) * 16;

    auto stageKV = [&](int b) {
        gload_lds16(gk,      &Ks[b][0][16 * w][0]);
        gload_lds16(gk + 64, &Ks[b][1][16 * w][0]);
        gk += (size_t)64 * QLD * 2;
        gload_lds16(gv,      &Vt[b][0][16 * w][0]);
        gload_lds16(gv + 64, &Vt[b][1][16 * w][0]);
        gv += 128;
    };
    stageKV(0);

    f32x4 oacc[4] = {};
    float rsum[4] = {0.0f, 0.0f, 0.0f, 0.0f};

    for (int t = 0; t < S_LEN / 64; ++t) {
        __syncthreads();                       // drains buf t's loads (and Q on t=0)
        if (t + 1 < S_LEN / 64) stageKV((t + 1) & 1);
        const int b = t & 1;
        const int kt = t * 64;

        // S = Q @ K^T
        f32x4 sacc[4] = {};
#pragma unroll
        for (int ks = 0; ks < 2; ++ks) {
            short8 aq = *(const short8*)&Qs[ks][16 * w + l15][quad * 8];
#pragma unroll
            for (int nt = 0; nt < 4; ++nt) {
                short8 bk = *(const short8*)&Ks[b][ks][nt * 16 + l15][quad * 8];
                sacc[nt] = __builtin_amdgcn_mfma_f32_16x16x32_bf16(aq, bk, sacc[nt], 0, 0, 0);
            }
        }

        // no-max softmax: p = exp2(s * 0.125*log2e + maskbias)
        float mb[4];
#pragma unroll
        for (int nt = 0; nt < 4; ++nt) mb[nt] = mbias[kt + nt * 16 + l15];
#pragma unroll
        for (int nt = 0; nt < 4; ++nt)
#pragma unroll
            for (int r = 0; r < 4; ++r) {
                float p = EXP2F(fmaf(sacc[nt][r], 0.18033688011112042f, mb[nt]));
                uint pu = __float_as_uint(p);
                rsum[r] += __uint_as_float(pu & 0xffff0000u);   // consistent w/ stored bf16
                Ps[w][nt >> 1][quad * 4 + r][(nt & 1) * 16 + l15] = (ushort)(pu >> 16);
            }

        // O += P @ V
#pragma unroll
        for (int ks = 0; ks < 2; ++ks) {
            short8 ap = *(const short8*)&Ps[w][ks][l15][quad * 8];
#pragma unroll
            for (int vt = 0; vt < 4; ++vt) {
                short8 bv = *(const short8*)&Vt[b][ks][vt * 16 + l15][quad * 8];
                oacc[vt] = __builtin_amdgcn_mfma_f32_16x16x32_bf16(ap, bv, oacc[vt], 0, 0, 0);
            }
        }
    }

    float inv[4];
#pragma unroll
    for (int r = 0; r < 4; ++r) {
        float s = rsum[r];
        s += __shfl_xor(s, 1);
        s += __shfl_xor(s, 2);
        s += __shfl_xor(s, 4);
        s += __shfl_xor(s, 8);
        inv[r] = 1.0f / s;
    }
#pragma unroll
    for (int vt = 0; vt < 4; ++vt)
#pragma unroll
        for (int r = 0; r < 4; ++r)
            o[(size_t)(q0 + 16 * w + quad * 4 + r) * D_DIM + hoff + vt * 16 + l15] =
                f2bf(oacc[vt][r] * inv[r]);
}

// ---------------------------------------------------------------------------
// ff2 split-K combine: out = x2 + b2[col] + p0 + p1
// ---------------------------------------------------------------------------
__global__ __launch_bounds__(256) void ff2_combine(
    const float* __restrict__ x2, const float* __restrict__ b2,
    const float* __restrict__ p0, const float* __restrict__ p1,
    float* __restrict__ out)
{
    size_t i = ((size_t)blockIdx.x * 256 + threadIdx.x) * 4;
    f32x4 a  = *(const f32x4*)(x2 + i);
    f32x4 q0 = *(const f32x4*)(p0 + i);
    f32x4 q1 = *(const f32x4*)(p1 + i);
    f32x4 bb = *(const f32x4*)(b2 + (int)(i & 511));
    f32x4 r = a + q0 + q1 + bb;
    *(f32x4*)(out + i) = r;
}

// ---------------------------------------------------------------------------
extern "C" void kernel_launch(void* const* d_in, const int* in_sizes, int n_in,
                              void* d_out, int out_size, void* d_ws, size_t ws_size,
                              hipStream_t stream) {
    (void)in_sizes; (void)n_in; (void)out_size; (void)ws_size;
    const float* x    = (const float*)d_in[0];
    const int*   mask = (const int*)d_in[1];
    const float* wq = (const float*)d_in[2];
    const float* bq = (const float*)d_in[3];
    const float* wk = (const float*)d_in[4];
    const float* bk = (const float*)d_in[5];
    const float* wv = (const float*)d_in[6];
    const float* bv = (const float*)d_in[7];
    const float* wo = (const float*)d_in[8];
    const float* bo = (const float*)d_in[9];
    const float* w1 = (const float*)d_in[10];
    const float* b1 = (const float*)d_in[11];
    const float* w2 = (const float*)d_in[12];
    const float* b2 = (const float*)d_in[13];
    const float* ln1a = (const float*)d_in[14];
    const float* ln1b = (const float*)d_in[15];
    const float* ln2a = (const float*)d_in[16];
    const float* ln2b = (const float*)d_in[17];
    float* out = (float*)d_out;

    char* p = (char*)d_ws;
    ushort* wqkvt = (ushort*)p; p += (size_t)1536 * 512 * 2;   // [1536][512]
    ushort* wot   = (ushort*)p; p += (size_t)512 * 512 * 2;
    ushort* w1t   = (ushort*)p; p += (size_t)2048 * 512 * 2;
    ushort* w2t   = (ushort*)p; p += (size_t)512 * 2048 * 2;
    float*  bqkv  = (float*)p;  p += 1536 * 4;
    float*  mbias = (float*)p;  p += 4096 * 4;
    ushort* h_bf  = (ushort*)p; p += (size_t)4096 * 512 * 2;    // also p0 region
    ushort* qkv   = (ushort*)p; p += (size_t)4096 * 1536 * 2;   // also p0/p1 region
    ushort* vbt   = (ushort*)p; p += (size_t)512 * 4096 * 2;
    ushort* at_bf = (ushort*)p; p += (size_t)4096 * 512 * 2;
    float*  x2    = (float*)p;  p += (size_t)4096 * 512 * 4;
    ushort* h2    = (ushort*)p; p += (size_t)4096 * 512 * 2;
    ushort* ff1   = (ushort*)p; p += (size_t)4096 * 2048 * 2;
    // split-K partials alias h_bf+qkv (dead after flash): 2 x 8.39 MB = 16.78 MB
    float*  pbuf  = (float*)h_bf;

    dim3 blk(256);

    // weight prep
    transpose_cast<<<dim3(16, 16), blk, 0, stream>>>(wq, wqkvt, 512, 512);
    transpose_cast<<<dim3(16, 16), blk, 0, stream>>>(wk, wqkvt + (size_t)512 * 512, 512, 512);
    transpose_cast<<<dim3(16, 16), blk, 0, stream>>>(wv, wqkvt + (size_t)1024 * 512, 512, 512);
    transpose_cast<<<dim3(16, 16), blk, 0, stream>>>(wo, wot, 512, 512);
    transpose_cast<<<dim3(64, 16), blk, 0, stream>>>(w1, w1t, 512, 2048);
    transpose_cast<<<dim3(16, 64), blk, 0, stream>>>(w2, w2t, 2048, 512);
    prep_kernel<<<dim3(16), blk, 0, stream>>>(bq, bk, bv, mask, bqkv, mbias);

    // LN1
    ln_kernel<<<dim3(S_LEN), blk, 0, stream>>>(x, ln1a, ln1b, h_bf);

    // fused QKV projection (V written transposed to vbt)
    gemm_mfma<<<dim3(24, 32, 1), blk, 0, stream>>>(
        h_bf, wqkvt, bqkv, nullptr, nullptr, qkv, vbt,
        S_LEN, 1536, 512, 0, 512);

    // flash attention
    flash_mfma<<<dim3(S_LEN / 64, H_NUM), blk, 0, stream>>>(qkv, vbt, mbias, at_bf);

    // output projection + residual(x) -> x2 (fp32)
    gemm_mfma<<<dim3(8, 32, 1), blk, 0, stream>>>(
        at_bf, wot, bo, x, x2, nullptr, nullptr,
        S_LEN, 512, 512, 0, 512);

    // LN2 -> h2 (bf16)
    ln_kernel<<<dim3(S_LEN), blk, 0, stream>>>(x2, ln2a, ln2b, h2);

    // FFN-1 (relu)
    gemm_mfma<<<dim3(32, 32, 1), blk, 0, stream>>>(
        h2, w1t, b1, nullptr, nullptr, ff1, nullptr,
        S_LEN, 2048, 512, 1, 512);

    // FFN-2 split-K=2 -> partials
    gemm_mfma<<<dim3(8, 32, 2), blk, 0, stream>>>(
        ff1, w2t, nullptr, nullptr, pbuf, nullptr, nullptr,
        S_LEN, 512, 2048, 0, 1024);

    // combine: out = x2 + b2 + p0 + p1
    ff2_combine<<<dim3(2048), blk, 0, stream>>>(
        x2, b2, pbuf, pbuf + (size_t)S_LEN * 512, out);
}

// Round 5
// 280.891 us; speedup vs baseline: 9.6059x; 1.0280x over previous
//
#include <hip/hip_runtime.h>
#include <hip/hip_bf16.h>

#define S_LEN 4096
#define D_DIM 512
#define H_NUM 8
#define DK_DIM 64
#define FF_DIM 2048
#define QLD 1536   // fused qkv row stride

typedef __attribute__((ext_vector_type(8))) short short8;
typedef __attribute__((ext_vector_type(4))) float f32x4;
typedef __attribute__((ext_vector_type(4))) ushort us4;

#if __has_builtin(__builtin_amdgcn_exp2f)
#define EXP2F __builtin_amdgcn_exp2f
#else
#define EXP2F exp2f
#endif

__device__ __forceinline__ ushort f2bf(float f) {
    union { float f; uint u; } v; v.f = f;
    uint r = v.u + 0x7FFF + ((v.u >> 16) & 1);
    return (ushort)(r >> 16);
}

__device__ __forceinline__ void gload_lds16(const void* g, void* l) {
    __builtin_amdgcn_global_load_lds(
        (const __attribute__((address_space(1))) void*)g,
        (__attribute__((address_space(3))) void*)l,
        16, 0, 0);
}

// ---------------------------------------------------------------------------
// One-launch prep: 6 weight transposes (fp32 [K][N] -> bf16 [N][K]) + bias
// concat + mask->additive-bias. Grid 3088.
// ---------------------------------------------------------------------------
__global__ __launch_bounds__(256) void prep_all(
    const float* __restrict__ wq, const float* __restrict__ wk,
    const float* __restrict__ wv, const float* __restrict__ wo,
    const float* __restrict__ w1, const float* __restrict__ w2,
    const float* __restrict__ bq, const float* __restrict__ bk,
    const float* __restrict__ bv, const int* __restrict__ mask,
    ushort* __restrict__ wqkvt, ushort* __restrict__ wot,
    ushort* __restrict__ w1t, ushort* __restrict__ w2t,
    float* __restrict__ bqkv, float* __restrict__ mbias)
{
    __shared__ float t[32][33];
    const int bid = blockIdx.x, tid = threadIdx.x;
    if (bid < 3072) {
        const float* src; ushort* dst; int K, N, tx, ty;
        if (bid < 1024) {          // wq/wk/wv/wo: 512x512, 256 tiles each
            int wsel = bid >> 8, id = bid & 255;
            src = wsel == 0 ? wq : wsel == 1 ? wk : wsel == 2 ? wv : wo;
            dst = wsel == 0 ? wqkvt : wsel == 1 ? wqkvt + 512 * 512
                : wsel == 2 ? wqkvt + 1024 * 512 : wot;
            K = 512; N = 512; tx = id & 15; ty = id >> 4;
        } else if (bid < 2048) {   // w1: [512][2048]
            int id = bid - 1024; src = w1; dst = w1t;
            K = 512; N = 2048; tx = id & 63; ty = id >> 6;
        } else {                   // w2: [2048][512]
            int id = bid - 2048; src = w2; dst = w2t;
            K = 2048; N = 512; tx = id & 15; ty = id >> 4;
        }
        int gn = tx * 32, gk = ty * 32;
        int lx = tid & 31, ly = tid >> 5;
#pragma unroll
        for (int i = 0; i < 32; i += 8)
            t[ly + i][lx] = src[(size_t)(gk + ly + i) * N + gn + lx];
        __syncthreads();
#pragma unroll
        for (int i = 0; i < 32; i += 8)
            dst[(size_t)(gn + ly + i) * K + gk + lx] = f2bf(t[lx][ly + i]);
    } else {
        int i = (bid - 3072) * 256 + tid;   // 0..4095
        if (i < 512)       bqkv[i] = bq[i];
        else if (i < 1024) bqkv[i] = bk[i - 512];
        else if (i < 1536) bqkv[i] = bv[i - 1024];
        mbias[i] = mask[i] ? 0.0f : -1e9f;
    }
}

// ---------------------------------------------------------------------------
// LN1: fp32 in -> bf16 out. Bessel var (torch.std), eps added to std.
// ---------------------------------------------------------------------------
__global__ __launch_bounds__(256) void ln1_kernel(
    const float* __restrict__ x,
    const float* __restrict__ aP, const float* __restrict__ bP,
    ushort* __restrict__ out)
{
    const int row = blockIdx.x;
    const int d = threadIdx.x * 2;
    float2 v = *(const float2*)(x + (size_t)row * D_DIM + d);
    float sum = v.x + v.y;
    float sq  = v.x * v.x + v.y * v.y;
#pragma unroll
    for (int off = 1; off < 64; off <<= 1) {
        sum += __shfl_xor(sum, off);
        sq  += __shfl_xor(sq, off);
    }
    __shared__ float ssum[4], ssq[4];
    int wid = threadIdx.x >> 6;
    if ((threadIdx.x & 63) == 0) { ssum[wid] = sum; ssq[wid] = sq; }
    __syncthreads();
    sum = ssum[0] + ssum[1] + ssum[2] + ssum[3];
    sq  = ssq[0] + ssq[1] + ssq[2] + ssq[3];
    float mean = sum * (1.0f / D_DIM);
    float var  = (sq - (float)D_DIM * mean * mean) * (1.0f / (D_DIM - 1));
    var = fmaxf(var, 0.0f);
    float scale = aP[0] / (sqrtf(var) + 1e-6f);
    float beta  = bP[0];
    ushort2 o;
    o.x = f2bf((v.x - mean) * scale + beta);
    o.y = f2bf((v.y - mean) * scale + beta);
    *(ushort2*)(out + (size_t)row * D_DIM + d) = o;
}

// ---------------------------------------------------------------------------
// LN2 fused with wo split-K combine: x2 = x + bo + p0 + p1 (stored, fp32),
// then LayerNorm(x2) -> h2 (bf16).
// ---------------------------------------------------------------------------
__global__ __launch_bounds__(256) void ln2_fused(
    const float* __restrict__ x, const float* __restrict__ bo,
    const float* __restrict__ p0, const float* __restrict__ p1,
    const float* __restrict__ aP, const float* __restrict__ bP,
    float* __restrict__ x2, ushort* __restrict__ h2)
{
    const int row = blockIdx.x;
    const int d = threadIdx.x * 2;
    const size_t idx = (size_t)row * D_DIM + d;
    float2 xv = *(const float2*)(x + idx);
    float2 a0 = *(const float2*)(p0 + idx);
    float2 a1 = *(const float2*)(p1 + idx);
    float2 bb = *(const float2*)(bo + d);
    float2 v;
    v.x = xv.x + a0.x + a1.x + bb.x;
    v.y = xv.y + a0.y + a1.y + bb.y;
    *(float2*)(x2 + idx) = v;
    float sum = v.x + v.y;
    float sq  = v.x * v.x + v.y * v.y;
#pragma unroll
    for (int off = 1; off < 64; off <<= 1) {
        sum += __shfl_xor(sum, off);
        sq  += __shfl_xor(sq, off);
    }
    __shared__ float ssum[4], ssq[4];
    int wid = threadIdx.x >> 6;
    if ((threadIdx.x & 63) == 0) { ssum[wid] = sum; ssq[wid] = sq; }
    __syncthreads();
    sum = ssum[0] + ssum[1] + ssum[2] + ssum[3];
    sq  = ssq[0] + ssq[1] + ssq[2] + ssq[3];
    float mean = sum * (1.0f / D_DIM);
    float var  = (sq - (float)D_DIM * mean * mean) * (1.0f / (D_DIM - 1));
    var = fmaxf(var, 0.0f);
    float scale = aP[0] / (sqrtf(var) + 1e-6f);
    float beta  = bP[0];
    ushort2 o;
    o.x = f2bf((v.x - mean) * scale + beta);
    o.y = f2bf((v.y - mean) * scale + beta);
    *(ushort2*)(h2 + idx) = o;
}

// ---------------------------------------------------------------------------
// MFMA bf16 GEMM, double-buffered async staging. 128x64 tile, 4 waves.
// ksl < K => split-K partial (raw fp32 to outF + z*M*N, no bias).
// outVT: QKV blocks with n0>=1024 write V transposed [dk][seq].
// bf16 output path goes through an LDS bounce -> global_store_dwordx4.
// ---------------------------------------------------------------------------
__global__ __launch_bounds__(256) void gemm_mfma(
    const ushort* __restrict__ A, const ushort* __restrict__ Bt,
    const float* __restrict__ bias,
    float* __restrict__ outF, ushort* __restrict__ outB,
    ushort* __restrict__ outVT,
    int M, int N, int K, int relu, int ksl)
{
    __shared__ ushort As[2][2][128][32];   // 32 KB
    __shared__ ushort Bs[2][2][64][32];    // 16 KB
    const int tid = threadIdx.x;
    const int w = tid >> 6, lane = tid & 63;
    const int l15 = lane & 15, quad = lane >> 4;
    const int m0 = blockIdx.y * 128, n0 = blockIdx.x * 64;
    const int kz = blockIdx.z;
    const int kbeg = kz * ksl;

    f32x4 acc[2][4] = {};

    const char* gA  = (const char*)(A  + (size_t)(m0 + 32 * w + lane / 4) * K + kbeg) + (lane % 4) * 16;
    const char* gA2 = gA + (size_t)16 * K * 2;
    const char* gB  = (const char*)(Bt + (size_t)(n0 + 16 * w + lane / 4) * K + kbeg) + (lane % 4) * 16;

    auto stage = [&](int b) {
        gload_lds16(gA,       &As[b][0][32 * w][0]);
        gload_lds16(gA + 64,  &As[b][1][32 * w][0]);
        gload_lds16(gA2,      &As[b][0][32 * w + 16][0]);
        gload_lds16(gA2 + 64, &As[b][1][32 * w + 16][0]);
        gload_lds16(gB,       &Bs[b][0][16 * w][0]);
        gload_lds16(gB + 64,  &Bs[b][1][16 * w][0]);
        gA += 128; gA2 += 128; gB += 128;
    };

    stage(0);
    const int nit = ksl >> 6;
    for (int t = 0; t < nit; ++t) {
        __syncthreads();
        if (t + 1 < nit) stage((t + 1) & 1);
        const int b = t & 1;
#pragma unroll
        for (int ks = 0; ks < 2; ++ks) {
            short8 a0 = *(const short8*)&As[b][ks][32 * w + l15][quad * 8];
            short8 a1 = *(const short8*)&As[b][ks][32 * w + 16 + l15][quad * 8];
            short8 b0 = *(const short8*)&Bs[b][ks][0 * 16 + l15][quad * 8];
            short8 b1 = *(const short8*)&Bs[b][ks][1 * 16 + l15][quad * 8];
            short8 b2 = *(const short8*)&Bs[b][ks][2 * 16 + l15][quad * 8];
            short8 b3 = *(const short8*)&Bs[b][ks][3 * 16 + l15][quad * 8];
            acc[0][0] = __builtin_amdgcn_mfma_f32_16x16x32_bf16(a0, b0, acc[0][0], 0, 0, 0);
            acc[0][1] = __builtin_amdgcn_mfma_f32_16x16x32_bf16(a0, b1, acc[0][1], 0, 0, 0);
            acc[0][2] = __builtin_amdgcn_mfma_f32_16x16x32_bf16(a0, b2, acc[0][2], 0, 0, 0);
            acc[0][3] = __builtin_amdgcn_mfma_f32_16x16x32_bf16(a0, b3, acc[0][3], 0, 0, 0);
            acc[1][0] = __builtin_amdgcn_mfma_f32_16x16x32_bf16(a1, b0, acc[1][0], 0, 0, 0);
            acc[1][1] = __builtin_amdgcn_mfma_f32_16x16x32_bf16(a1, b1, acc[1][1], 0, 0, 0);
            acc[1][2] = __builtin_amdgcn_mfma_f32_16x16x32_bf16(a1, b2, acc[1][2], 0, 0, 0);
            acc[1][3] = __builtin_amdgcn_mfma_f32_16x16x32_bf16(a1, b3, acc[1][3], 0, 0, 0);
        }
    }

    // ---- epilogues
    if (ksl < K) {   // split-K partial: raw fp32, no bias
        float* of = outF + (size_t)kz * M * N;
#pragma unroll
        for (int mt = 0; mt < 2; ++mt)
#pragma unroll
            for (int nt = 0; nt < 4; ++nt)
#pragma unroll
                for (int r = 0; r < 4; ++r) {
                    int mm = m0 + 32 * w + mt * 16 + quad * 4 + r;
                    int nn = n0 + nt * 16 + l15;
                    of[(size_t)mm * N + nn] = acc[mt][nt][r];
                }
        return;
    }

    if (outVT && n0 >= 1024) {   // V columns of fused QKV: write transposed
#pragma unroll
        for (int mt = 0; mt < 2; ++mt)
#pragma unroll
            for (int nt = 0; nt < 4; ++nt) {
                int nn = n0 + nt * 16 + l15;
                int mmb = m0 + 32 * w + mt * 16 + quad * 4;
                us4 pk;
#pragma unroll
                for (int r = 0; r < 4; ++r)
                    pk[r] = (short)f2bf(acc[mt][nt][r] + bias[nn]);
                *(us4*)(outVT + (size_t)(nn - 1024) * S_LEN + mmb) = pk;
            }
        return;
    }

    // bf16 out via LDS bounce (coalesced 16B stores). Es aliases As.
    ushort (*Es)[32][68] = (ushort (*)[32][68])&As[0][0][0][0];
    __syncthreads();   // all waves done reading As
#pragma unroll
    for (int mt = 0; mt < 2; ++mt)
#pragma unroll
        for (int nt = 0; nt < 4; ++nt)
#pragma unroll
            for (int r = 0; r < 4; ++r) {
                float v = acc[mt][nt][r] + bias[n0 + nt * 16 + l15];
                if (relu) v = fmaxf(v, 0.0f);
                Es[w][mt * 16 + quad * 4 + r][nt * 16 + l15] = f2bf(v);
            }
    __syncthreads();
#pragma unroll
    for (int p = 0; p < 4; ++p) {
        int row = p * 8 + (lane >> 3);
        int col = (lane & 7) * 8;
        short8 vv = *(const short8*)&Es[w][row][col];
        *(short8*)(outB + (size_t)(m0 + 32 * w + row) * N + n0 + col) = vv;
    }
}

// ---------------------------------------------------------------------------
// MFMA bf16 flash attention, split-KV x2, no-max softmax, ones-MFMA rowsum.
// Block = 64 q-rows x 1 head x 1 kv-half. Outputs fp32 partial O and l.
// ---------------------------------------------------------------------------
__global__ __launch_bounds__(256) void flash_mfma(
    const ushort* __restrict__ qkv, const ushort* __restrict__ vbt,
    const float* __restrict__ mbias,
    float* __restrict__ pO, float* __restrict__ pl)
{
    __shared__ ushort Qs[2][64][32];       //  8 KB
    __shared__ ushort Ks[2][2][64][32];    // 16 KB [buf][ks][key][dk%32]
    __shared__ ushort Vt[2][2][64][32];    // 16 KB [buf][ks][dk][key%32]
    __shared__ ushort Ps[4][2][16][36];    //  9 KB [wave][ks][qrow][key(pad)]

    const int head = blockIdx.y;
    const int q0 = blockIdx.x * 64;
    const int half = blockIdx.z;
    const int kvbeg = half * (S_LEN / 2);
    const int tid = threadIdx.x;
    const int w = tid >> 6, lane = tid & 63;
    const int l15 = lane & 15, quad = lane >> 4;
    const int hoff = head * DK_DIM;

    {
        const char* gq = (const char*)(qkv + (size_t)(q0 + 16 * w + lane / 4) * QLD + hoff)
                         + (lane % 4) * 16;
        gload_lds16(gq,      &Qs[0][16 * w][0]);
        gload_lds16(gq + 64, &Qs[1][16 * w][0]);
    }

    const char* gk = (const char*)(qkv + (size_t)(kvbeg + 16 * w + lane / 4) * QLD + 512 + hoff)
                     + (lane % 4) * 16;
    const char* gv = (const char*)(vbt + (size_t)(hoff + 16 * w + lane / 4) * S_LEN + kvbeg)
                     + (lane % 4) * 16;

    auto stageKV = [&](int b) {
        gload_lds16(gk,      &Ks[b][0][16 * w][0]);
        gload_lds16(gk + 64, &Ks[b][1][16 * w][0]);
        gk += (size_t)64 * QLD * 2;
        gload_lds16(gv,      &Vt[b][0][16 * w][0]);
        gload_lds16(gv + 64, &Vt[b][1][16 * w][0]);
        gv += 128;
    };
    stageKV(0);

    const short8 ones = {0x3F80, 0x3F80, 0x3F80, 0x3F80,
                         0x3F80, 0x3F80, 0x3F80, 0x3F80};
    f32x4 oacc[4] = {};
    f32x4 lacc = {};

    const int NIT = (S_LEN / 2) / 64;
    for (int t = 0; t < NIT; ++t) {
        __syncthreads();
        if (t + 1 < NIT) stageKV((t + 1) & 1);
        const int b = t & 1;
        const int ktg = kvbeg + t * 64;

        // S = Q @ K^T
        f32x4 sacc[4] = {};
#pragma unroll
        for (int ks = 0; ks < 2; ++ks) {
            short8 aq = *(const short8*)&Qs[ks][16 * w + l15][quad * 8];
#pragma unroll
            for (int nt = 0; nt < 4; ++nt) {
                short8 bk = *(const short8*)&Ks[b][ks][nt * 16 + l15][quad * 8];
                sacc[nt] = __builtin_amdgcn_mfma_f32_16x16x32_bf16(aq, bk, sacc[nt], 0, 0, 0);
            }
        }

        // p = exp2(s*0.125*log2e + maskbias), truncate to bf16
        float mb[4];
#pragma unroll
        for (int nt = 0; nt < 4; ++nt) mb[nt] = mbias[ktg + nt * 16 + l15];
#pragma unroll
        for (int nt = 0; nt < 4; ++nt)
#pragma unroll
            for (int r = 0; r < 4; ++r) {
                float p = EXP2F(fmaf(sacc[nt][r], 0.18033688011112042f, mb[nt]));
                Ps[w][nt >> 1][quad * 4 + r][(nt & 1) * 16 + l15] =
                    (ushort)(__float_as_uint(p) >> 16);
            }

        // O += P @ V ; l += P @ 1 (rowsum via MFMA, consistent with stored P)
#pragma unroll
        for (int ks = 0; ks < 2; ++ks) {
            short8 ap = *(const short8*)&Ps[w][ks][l15][quad * 8];
            lacc = __builtin_amdgcn_mfma_f32_16x16x32_bf16(ap, ones, lacc, 0, 0, 0);
#pragma unroll
            for (int vt = 0; vt < 4; ++vt) {
                short8 bv = *(const short8*)&Vt[b][ks][vt * 16 + l15][quad * 8];
                oacc[vt] = __builtin_amdgcn_mfma_f32_16x16x32_bf16(ap, bv, oacc[vt], 0, 0, 0);
            }
        }
    }

    // partial O (fp32, coalesced dwords) + partial l
    float* pOh = pO + (size_t)half * S_LEN * D_DIM;
#pragma unroll
    for (int vt = 0; vt < 4; ++vt)
#pragma unroll
        for (int r = 0; r < 4; ++r)
            pOh[(size_t)(q0 + 16 * w + quad * 4 + r) * D_DIM + hoff + vt * 16 + l15] =
                oacc[vt][r];
    if (l15 == 0) {
#pragma unroll
        for (int r = 0; r < 4; ++r)
            pl[((size_t)half * H_NUM + head) * S_LEN + q0 + 16 * w + quad * 4 + r] = lacc[r];
    }
}

// ---------------------------------------------------------------------------
// Flash split-KV combine: at = (O0+O1)/(l0+l1), bf16 out.
// ---------------------------------------------------------------------------
__global__ __launch_bounds__(256) void flash_comb(
    const float* __restrict__ pO, const float* __restrict__ pl,
    ushort* __restrict__ at_bf)
{
    const size_t SD = (size_t)S_LEN * D_DIM;
    size_t i = ((size_t)blockIdx.x * 256 + threadIdx.x) * 4;
    int s = (int)(i >> 9), d = (int)(i & 511), head = d >> 6;
    float l = pl[(size_t)head * S_LEN + s] +
              pl[((size_t)H_NUM + head) * S_LEN + s];
    f32x4 a = *(const f32x4*)(pO + i);
    f32x4 b = *(const f32x4*)(pO + SD + i);
    float inv = 1.0f / l;
    us4 pk;
#pragma unroll
    for (int j = 0; j < 4; ++j) pk[j] = (short)f2bf((a[j] + b[j]) * inv);
    *(us4*)(at_bf + i) = pk;
}

// ---------------------------------------------------------------------------
// ff2 split-K combine: out = x2 + b2[col] + p0 + p1 (fp32)
// ---------------------------------------------------------------------------
__global__ __launch_bounds__(256) void ff2_combine(
    const float* __restrict__ x2, const float* __restrict__ b2,
    const float* __restrict__ p0, const float* __restrict__ p1,
    float* __restrict__ out)
{
    size_t i = ((size_t)blockIdx.x * 256 + threadIdx.x) * 4;
    f32x4 a  = *(const f32x4*)(x2 + i);
    f32x4 q0 = *(const f32x4*)(p0 + i);
    f32x4 q1 = *(const f32x4*)(p1 + i);
    f32x4 bb = *(const f32x4*)(b2 + (int)(i & 511));
    f32x4 r = a + q0 + q1 + bb;
    *(f32x4*)(out + i) = r;
}

// ---------------------------------------------------------------------------
extern "C" void kernel_launch(void* const* d_in, const int* in_sizes, int n_in,
                              void* d_out, int out_size, void* d_ws, size_t ws_size,
                              hipStream_t stream) {
    (void)in_sizes; (void)n_in; (void)out_size; (void)ws_size;
    const float* x    = (const float*)d_in[0];
    const int*   mask = (const int*)d_in[1];
    const float* wq = (const float*)d_in[2];
    const float* bq = (const float*)d_in[3];
    const float* wk = (const float*)d_in[4];
    const float* bk = (const float*)d_in[5];
    const float* wv = (const float*)d_in[6];
    const float* bv = (const float*)d_in[7];
    const float* wo = (const float*)d_in[8];
    const float* bo = (const float*)d_in[9];
    const float* w1 = (const float*)d_in[10];
    const float* b1 = (const float*)d_in[11];
    const float* w2 = (const float*)d_in[12];
    const float* b2 = (const float*)d_in[13];
    const float* ln1a = (const float*)d_in[14];
    const float* ln1b = (const float*)d_in[15];
    const float* ln2a = (const float*)d_in[16];
    const float* ln2b = (const float*)d_in[17];
    float* out = (float*)d_out;

    const size_t SD = (size_t)S_LEN * D_DIM;
    char* p = (char*)d_ws;
    ushort* wqkvt = (ushort*)p; p += (size_t)1536 * 512 * 2;
    ushort* wot   = (ushort*)p; p += (size_t)512 * 512 * 2;
    ushort* w1t   = (ushort*)p; p += (size_t)2048 * 512 * 2;
    ushort* w2t   = (ushort*)p; p += (size_t)512 * 2048 * 2;
    float*  bqkv  = (float*)p;  p += 1536 * 4;
    float*  mbias = (float*)p;  p += 4096 * 4;
    float*  pl    = (float*)p;  p += (size_t)2 * H_NUM * S_LEN * 4;
    ushort* h_bf  = (ushort*)p; p += SD * 2;                    // \ also wopart /
    ushort* qkv   = (ushort*)p; p += (size_t)4096 * 1536 * 2;   // /  ff2part 16MB
    ushort* vbt   = (ushort*)p; p += SD * 2;
    ushort* at_bf = (ushort*)p; p += SD * 2;
    float*  x2    = (float*)p;  p += SD * 4;
    ushort* h2    = (ushort*)p; p += SD * 2;
    ushort* ff1   = (ushort*)p; p += (size_t)4096 * 2048 * 2;   // also pO 16MB
    float* pO      = (float*)ff1;     // flash partials: 2 x SD fp32
    float* wopart  = (float*)h_bf;    // wo partials: 2 x SD fp32
    float* ff2part = (float*)h_bf;    // ff2 partials: 2 x SD fp32

    dim3 blk(256);

    prep_all<<<dim3(3088), blk, 0, stream>>>(wq, wk, wv, wo, w1, w2, bq, bk, bv,
                                             mask, wqkvt, wot, w1t, w2t, bqkv, mbias);

    ln1_kernel<<<dim3(S_LEN), blk, 0, stream>>>(x, ln1a, ln1b, h_bf);

    // fused QKV projection (V written transposed to vbt)
    gemm_mfma<<<dim3(24, 32, 1), blk, 0, stream>>>(
        h_bf, wqkvt, bqkv, nullptr, qkv, vbt, S_LEN, 1536, 512, 0, 512);

    // flash attention, split-KV x2
    flash_mfma<<<dim3(S_LEN / 64, H_NUM, 2), blk, 0, stream>>>(qkv, vbt, mbias, pO, pl);
    flash_comb<<<dim3(2048), blk, 0, stream>>>(pO, pl, at_bf);

    // output projection, split-K x2 -> partials (bias/residual in ln2_fused)
    gemm_mfma<<<dim3(8, 32, 2), blk, 0, stream>>>(
        at_bf, wot, nullptr, wopart, nullptr, nullptr, S_LEN, 512, 512, 0, 256);

    // x2 = x + bo + partials ; h2 = LN(x2)
    ln2_fused<<<dim3(S_LEN), blk, 0, stream>>>(x, bo, wopart, wopart + SD,
                                               ln2a, ln2b, x2, h2);

    // FFN-1 (relu)
    gemm_mfma<<<dim3(32, 32, 1), blk, 0, stream>>>(
        h2, w1t, b1, nullptr, ff1, nullptr, S_LEN, 2048, 512, 1, 512);

    // FFN-2 split-K x2 -> partials
    gemm_mfma<<<dim3(8, 32, 2), blk, 0, stream>>>(
        ff1, w2t, nullptr, ff2part, nullptr, nullptr, S_LEN, 512, 2048, 0, 1024);

    // out = x2 + b2 + p0 + p1
    ff2_combine<<<dim3(2048), blk, 0, stream>>>(
        x2, b2, ff2part, ff2part + SD, out);
}

// Round 6
// 242.546 us; speedup vs baseline: 11.1245x; 1.1581x over previous
//
#include <hip/hip_runtime.h>
#include <hip/hip_bf16.h>

#define S_LEN 4096
#define D_DIM 512
#define H_NUM 8
#define DK_DIM 64
#define FF_DIM 2048
#define QLD 1536   // fused qkv row stride

typedef __attribute__((ext_vector_type(8))) short short8;
typedef __attribute__((ext_vector_type(4))) float f32x4;
typedef __attribute__((ext_vector_type(4))) ushort us4;

#if __has_builtin(__builtin_amdgcn_exp2f)
#define EXP2F __builtin_amdgcn_exp2f
#else
#define EXP2F exp2f
#endif

__device__ __forceinline__ ushort f2bf(float f) {
    union { float f; uint u; } v; v.f = f;
    uint r = v.u + 0x7FFF + ((v.u >> 16) & 1);
    return (ushort)(r >> 16);
}

__device__ __forceinline__ void gload_lds16(const void* g, void* l) {
    __builtin_amdgcn_global_load_lds(
        (const __attribute__((address_space(1))) void*)g,
        (__attribute__((address_space(3))) void*)l,
        16, 0, 0);
}

#define MFMA16(a, b, c) __builtin_amdgcn_mfma_f32_16x16x32_bf16(a, b, c, 0, 0, 0)

// ---------------------------------------------------------------------------
// One-launch prep: 6 weight transposes (fp32 [K][N] -> bf16 [N][K]) + bias
// concat + mask->additive-bias. Grid 3088.
// ---------------------------------------------------------------------------
__global__ __launch_bounds__(256) void prep_all(
    const float* __restrict__ wq, const float* __restrict__ wk,
    const float* __restrict__ wv, const float* __restrict__ wo,
    const float* __restrict__ w1, const float* __restrict__ w2,
    const float* __restrict__ bq, const float* __restrict__ bk,
    const float* __restrict__ bv, const int* __restrict__ mask,
    ushort* __restrict__ wqkvt, ushort* __restrict__ wot,
    ushort* __restrict__ w1t, ushort* __restrict__ w2t,
    float* __restrict__ bqkv, float* __restrict__ mbias)
{
    __shared__ float t[32][33];
    const int bid = blockIdx.x, tid = threadIdx.x;
    if (bid < 3072) {
        const float* src; ushort* dst; int K, N, tx, ty;
        if (bid < 1024) {
            int wsel = bid >> 8, id = bid & 255;
            src = wsel == 0 ? wq : wsel == 1 ? wk : wsel == 2 ? wv : wo;
            dst = wsel == 0 ? wqkvt : wsel == 1 ? wqkvt + 512 * 512
                : wsel == 2 ? wqkvt + 1024 * 512 : wot;
            K = 512; N = 512; tx = id & 15; ty = id >> 4;
        } else if (bid < 2048) {
            int id = bid - 1024; src = w1; dst = w1t;
            K = 512; N = 2048; tx = id & 63; ty = id >> 6;
        } else {
            int id = bid - 2048; src = w2; dst = w2t;
            K = 2048; N = 512; tx = id & 15; ty = id >> 4;
        }
        int gn = tx * 32, gk = ty * 32;
        int lx = tid & 31, ly = tid >> 5;
#pragma unroll
        for (int i = 0; i < 32; i += 8)
            t[ly + i][lx] = src[(size_t)(gk + ly + i) * N + gn + lx];
        __syncthreads();
#pragma unroll
        for (int i = 0; i < 32; i += 8)
            dst[(size_t)(gn + ly + i) * K + gk + lx] = f2bf(t[lx][ly + i]);
    } else {
        int i = (bid - 3072) * 256 + tid;
        if (i < 512)       bqkv[i] = bq[i];
        else if (i < 1024) bqkv[i] = bk[i - 512];
        else if (i < 1536) bqkv[i] = bv[i - 1024];
        mbias[i] = mask[i] ? 0.0f : -1e9f;
    }
}

// ---------------------------------------------------------------------------
// LN1: fp32 in -> bf16 out.
// ---------------------------------------------------------------------------
__global__ __launch_bounds__(256) void ln1_kernel(
    const float* __restrict__ x,
    const float* __restrict__ aP, const float* __restrict__ bP,
    ushort* __restrict__ out)
{
    const int row = blockIdx.x;
    const int d = threadIdx.x * 2;
    float2 v = *(const float2*)(x + (size_t)row * D_DIM + d);
    float sum = v.x + v.y;
    float sq  = v.x * v.x + v.y * v.y;
#pragma unroll
    for (int off = 1; off < 64; off <<= 1) {
        sum += __shfl_xor(sum, off);
        sq  += __shfl_xor(sq, off);
    }
    __shared__ float ssum[4], ssq[4];
    int wid = threadIdx.x >> 6;
    if ((threadIdx.x & 63) == 0) { ssum[wid] = sum; ssq[wid] = sq; }
    __syncthreads();
    sum = ssum[0] + ssum[1] + ssum[2] + ssum[3];
    sq  = ssq[0] + ssq[1] + ssq[2] + ssq[3];
    float mean = sum * (1.0f / D_DIM);
    float var  = (sq - (float)D_DIM * mean * mean) * (1.0f / (D_DIM - 1));
    var = fmaxf(var, 0.0f);
    float scale = aP[0] / (sqrtf(var) + 1e-6f);
    float beta  = bP[0];
    ushort2 o;
    o.x = f2bf((v.x - mean) * scale + beta);
    o.y = f2bf((v.y - mean) * scale + beta);
    *(ushort2*)(out + (size_t)row * D_DIM + d) = o;
}

// ---------------------------------------------------------------------------
// LN2 fused with wo split-K combine.
// ---------------------------------------------------------------------------
__global__ __launch_bounds__(256) void ln2_fused(
    const float* __restrict__ x, const float* __restrict__ bo,
    const float* __restrict__ p0, const float* __restrict__ p1,
    const float* __restrict__ aP, const float* __restrict__ bP,
    float* __restrict__ x2, ushort* __restrict__ h2)
{
    const int row = blockIdx.x;
    const int d = threadIdx.x * 2;
    const size_t idx = (size_t)row * D_DIM + d;
    float2 xv = *(const float2*)(x + idx);
    float2 a0 = *(const float2*)(p0 + idx);
    float2 a1 = *(const float2*)(p1 + idx);
    float2 bb = *(const float2*)(bo + d);
    float2 v;
    v.x = xv.x + a0.x + a1.x + bb.x;
    v.y = xv.y + a0.y + a1.y + bb.y;
    *(float2*)(x2 + idx) = v;
    float sum = v.x + v.y;
    float sq  = v.x * v.x + v.y * v.y;
#pragma unroll
    for (int off = 1; off < 64; off <<= 1) {
        sum += __shfl_xor(sum, off);
        sq  += __shfl_xor(sq, off);
    }
    __shared__ float ssum[4], ssq[4];
    int wid = threadIdx.x >> 6;
    if ((threadIdx.x & 63) == 0) { ssum[wid] = sum; ssq[wid] = sq; }
    __syncthreads();
    sum = ssum[0] + ssum[1] + ssum[2] + ssum[3];
    sq  = ssq[0] + ssq[1] + ssq[2] + ssq[3];
    float mean = sum * (1.0f / D_DIM);
    float var  = (sq - (float)D_DIM * mean * mean) * (1.0f / (D_DIM - 1));
    var = fmaxf(var, 0.0f);
    float scale = aP[0] / (sqrtf(var) + 1e-6f);
    float beta  = bP[0];
    ushort2 o;
    o.x = f2bf((v.x - mean) * scale + beta);
    o.y = f2bf((v.y - mean) * scale + beta);
    *(ushort2*)(h2 + idx) = o;
}

// ---------------------------------------------------------------------------
// MFMA bf16 GEMM, double-buffered async staging, XOR bank swizzle.
// ---------------------------------------------------------------------------
__global__ __launch_bounds__(256) void gemm_mfma(
    const ushort* __restrict__ A, const ushort* __restrict__ Bt,
    const float* __restrict__ bias,
    float* __restrict__ outF, ushort* __restrict__ outB,
    ushort* __restrict__ outVT,
    int M, int N, int K, int relu, int ksl)
{
    __shared__ ushort As[2][2][128][32];   // 32 KB
    __shared__ ushort Bs[2][2][64][32];    // 16 KB
    const int tid = threadIdx.x;
    const int w = tid >> 6, lane = tid & 63;
    const int l15 = lane & 15, quad = lane >> 4;
    const int sw = (l15 >> 1) & 3;                              // read swizzle
    const int swc = ((lane & 3) ^ ((lane >> 3) & 3)) * 16;      // stage swizzle (bytes)
    const int m0 = blockIdx.y * 128, n0 = blockIdx.x * 64;
    const int kz = blockIdx.z;
    const int kbeg = kz * ksl;

    f32x4 acc[2][4] = {};

    const char* gA  = (const char*)(A  + (size_t)(m0 + 32 * w + (lane >> 2)) * K + kbeg) + swc;
    const char* gA2 = gA + (size_t)16 * K * 2;
    const char* gB  = (const char*)(Bt + (size_t)(n0 + 16 * w + (lane >> 2)) * K + kbeg) + swc;

    auto stage = [&](int b) {
        gload_lds16(gA,       &As[b][0][32 * w][0]);
        gload_lds16(gA + 64,  &As[b][1][32 * w][0]);
        gload_lds16(gA2,      &As[b][0][32 * w + 16][0]);
        gload_lds16(gA2 + 64, &As[b][1][32 * w + 16][0]);
        gload_lds16(gB,       &Bs[b][0][16 * w][0]);
        gload_lds16(gB + 64,  &Bs[b][1][16 * w][0]);
        gA += 128; gA2 += 128; gB += 128;
    };

    stage(0);
    const int nit = ksl >> 6;
    for (int t = 0; t < nit; ++t) {
        __syncthreads();
        if (t + 1 < nit) stage((t + 1) & 1);
        const int b = t & 1;
#pragma unroll
        for (int ks = 0; ks < 2; ++ks) {
            short8 a0 = *(const short8*)&As[b][ks][32 * w + l15][(quad ^ sw) * 8];
            short8 a1 = *(const short8*)&As[b][ks][32 * w + 16 + l15][(quad ^ sw) * 8];
            short8 b0 = *(const short8*)&Bs[b][ks][0 * 16 + l15][(quad ^ sw) * 8];
            short8 b1 = *(const short8*)&Bs[b][ks][1 * 16 + l15][(quad ^ sw) * 8];
            short8 b2 = *(const short8*)&Bs[b][ks][2 * 16 + l15][(quad ^ sw) * 8];
            short8 b3 = *(const short8*)&Bs[b][ks][3 * 16 + l15][(quad ^ sw) * 8];
            acc[0][0] = MFMA16(a0, b0, acc[0][0]);
            acc[0][1] = MFMA16(a0, b1, acc[0][1]);
            acc[0][2] = MFMA16(a0, b2, acc[0][2]);
            acc[0][3] = MFMA16(a0, b3, acc[0][3]);
            acc[1][0] = MFMA16(a1, b0, acc[1][0]);
            acc[1][1] = MFMA16(a1, b1, acc[1][1]);
            acc[1][2] = MFMA16(a1, b2, acc[1][2]);
            acc[1][3] = MFMA16(a1, b3, acc[1][3]);
        }
    }

    if (ksl < K) {   // split-K partial
        float* of = outF + (size_t)kz * M * N;
#pragma unroll
        for (int mt = 0; mt < 2; ++mt)
#pragma unroll
            for (int nt = 0; nt < 4; ++nt)
#pragma unroll
                for (int r = 0; r < 4; ++r) {
                    int mm = m0 + 32 * w + mt * 16 + quad * 4 + r;
                    int nn = n0 + nt * 16 + l15;
                    of[(size_t)mm * N + nn] = acc[mt][nt][r];
                }
        return;
    }

    if (outVT && n0 >= 1024) {   // V columns of fused QKV: write transposed
#pragma unroll
        for (int mt = 0; mt < 2; ++mt)
#pragma unroll
            for (int nt = 0; nt < 4; ++nt) {
                int nn = n0 + nt * 16 + l15;
                int mmb = m0 + 32 * w + mt * 16 + quad * 4;
                us4 pk;
#pragma unroll
                for (int r = 0; r < 4; ++r)
                    pk[r] = (short)f2bf(acc[mt][nt][r] + bias[nn]);
                *(us4*)(outVT + (size_t)(nn - 1024) * S_LEN + mmb) = pk;
            }
        return;
    }

    // bf16 out via LDS bounce (coalesced 16B stores). Es aliases As.
    ushort (*Es)[32][68] = (ushort (*)[32][68])&As[0][0][0][0];
    __syncthreads();
#pragma unroll
    for (int mt = 0; mt < 2; ++mt)
#pragma unroll
        for (int nt = 0; nt < 4; ++nt)
#pragma unroll
            for (int r = 0; r < 4; ++r) {
                float v = acc[mt][nt][r] + bias[n0 + nt * 16 + l15];
                if (relu) v = fmaxf(v, 0.0f);
                Es[w][mt * 16 + quad * 4 + r][nt * 16 + l15] = f2bf(v);
            }
    __syncthreads();
#pragma unroll
    for (int p = 0; p < 4; ++p) {
        int row = p * 8 + (lane >> 3);
        int col = (lane & 7) * 8;
        short8 vv = *(const short8*)&Es[w][row][col];
        *(short8*)(outB + (size_t)(m0 + 32 * w + row) * N + n0 + col) = vv;
    }
}

// ---------------------------------------------------------------------------
// MFMA bf16 flash attention v3.
// Block = 64 q x 1 head (grid 512, head = bid&7 for XCD locality).
// Iter = 128 keys; wave w owns keys 32w..32w+31 (accumulates partial O,l over
// its key quarter; cross-wave reduce at end). Computes S^T = K@Q^T so P is
// written with b64 stores into per-wave Pld[q][key]; PV reads A-frags from it.
// Q fragments live in registers. l via ones-MFMA (consistent with stored P).
// ---------------------------------------------------------------------------
__global__ __launch_bounds__(256, 2) void flash_mfma(
    const ushort* __restrict__ qkv, const ushort* __restrict__ vbt,
    const float* __restrict__ mbias, ushort* __restrict__ at_bf)
{
    __shared__ ushort Qs[2][64][32];     //  8 KB [dkpanel][q][dk%32]
    __shared__ ushort Ks[2][128][32];    // 16 KB [dkpanel][key][dk%32]
    __shared__ ushort Vt[4][64][32];     // 16 KB [keypanel][dk][key%32]
    __shared__ ushort Pld[4][64][40];    // 20 KB [wave][q][key pad40]

    const int bid = blockIdx.x;
    const int head = bid & 7;
    const int q0 = (bid >> 3) * 64;
    const int tid = threadIdx.x;
    const int w = tid >> 6, lane = tid & 63;
    const int l15 = lane & 15, quad = lane >> 4;
    const int hoff = head * DK_DIM;
    const int sw = (l15 >> 1) & 3;
    const int swc = ((lane & 3) ^ ((lane >> 3) & 3)) * 16;

    // ---- stage Q once (wave w: rows 16w..16w+15, both dk panels)
    {
        const char* gq = (const char*)(qkv + (size_t)(q0 + 16 * w + (lane >> 2)) * QLD + hoff) + swc;
        gload_lds16(gq,      &Qs[0][16 * w][0]);
        gload_lds16(gq + 64, &Qs[1][16 * w][0]);
    }
    __syncthreads();
    short8 qf[2][4];
#pragma unroll
    for (int ks = 0; ks < 2; ++ks)
#pragma unroll
        for (int nt = 0; nt < 4; ++nt)
            qf[ks][nt] = *(const short8*)&Qs[ks][nt * 16 + l15][(quad ^ sw) * 8];

    const char* gk0 = (const char*)(qkv + (size_t)(32 * w + (lane >> 2)) * QLD + 512 + hoff) + swc;
    const char* gv0 = (const char*)(vbt + (size_t)(lane >> 2) * S_LEN + w * 32) + swc;

    const short8 ones = {0x3F80, 0x3F80, 0x3F80, 0x3F80,
                         0x3F80, 0x3F80, 0x3F80, 0x3F80};
    f32x4 oacc[4][4] = {};   // [mt_q][nt_dk]
    f32x4 lacc[4] = {};

    for (int t = 0; t < S_LEN / 128; ++t) {
        const int ktg = t * 128;
        __syncthreads();   // readers of previous K/V tile done
        {
            const char* gk = gk0 + (size_t)ktg * (QLD * 2);
            gload_lds16(gk,                        &Ks[0][32 * w][0]);
            gload_lds16(gk + (size_t)16 * QLD * 2, &Ks[0][32 * w + 16][0]);
            gload_lds16(gk + 64,                   &Ks[1][32 * w][0]);
            gload_lds16(gk + (size_t)16 * QLD * 2 + 64, &Ks[1][32 * w + 16][0]);
            const char* gv = gv0 + ktg * 2;
            gload_lds16(gv,                          &Vt[w][0][0]);
            gload_lds16(gv + (size_t)16 * S_LEN * 2, &Vt[w][16][0]);
            gload_lds16(gv + (size_t)32 * S_LEN * 2, &Vt[w][32][0]);
            gload_lds16(gv + (size_t)48 * S_LEN * 2, &Vt[w][48][0]);
        }
        __syncthreads();   // staging complete

        // ---- S^T = K @ Q^T for this wave's 32-key strip
        f32x4 sacc[2][4] = {};
#pragma unroll
        for (int ks = 0; ks < 2; ++ks) {
            short8 kf0 = *(const short8*)&Ks[ks][32 * w + l15][(quad ^ sw) * 8];
            short8 kf1 = *(const short8*)&Ks[ks][32 * w + 16 + l15][(quad ^ sw) * 8];
#pragma unroll
            for (int nt = 0; nt < 4; ++nt) {
                sacc[0][nt] = MFMA16(kf0, qf[ks][nt], sacc[0][nt]);
                sacc[1][nt] = MFMA16(kf1, qf[ks][nt], sacc[1][nt]);
            }
        }

        // ---- p = exp2(s*0.125*log2e + maskbias); b64 store to Pld[q][key]
#pragma unroll
        for (int mt = 0; mt < 2; ++mt) {
            f32x4 mb = *(const f32x4*)&mbias[ktg + 32 * w + mt * 16 + quad * 4];
#pragma unroll
            for (int nt = 0; nt < 4; ++nt) {
                us4 pk;
#pragma unroll
                for (int r = 0; r < 4; ++r) {
                    float p = EXP2F(fmaf(sacc[mt][nt][r], 0.18033688011112042f, mb[r]));
                    pk[r] = (ushort)(__float_as_uint(p) >> 16);
                }
                *(us4*)&Pld[w][nt * 16 + l15][mt * 16 + quad * 4] = pk;
            }
        }

        // ---- O += P @ V_strip ; l += P @ 1
#pragma unroll
        for (int mt = 0; mt < 4; ++mt) {
            short8 ap = *(const short8*)&Pld[w][mt * 16 + l15][quad * 8];
            lacc[mt] = MFMA16(ap, ones, lacc[mt]);
#pragma unroll
            for (int nt = 0; nt < 4; ++nt) {
                short8 bv = *(const short8*)&Vt[w][nt * 16 + l15][(quad ^ sw) * 8];
                oacc[mt][nt] = MFMA16(ap, bv, oacc[mt][nt]);
            }
        }
    }

    // ---- cross-wave reduction: O = sum_w oacc, l = sum_w lacc, write bf16
    float* Ored = (float*)&Pld[0][0][0];   // [4w][16q][68] fp32 (17.4 KB)
    float* lred = (float*)&Qs[0][0][0];    // [4w][64q] fp32
    if (l15 == 0) {
#pragma unroll
        for (int mt = 0; mt < 4; ++mt)
#pragma unroll
            for (int r = 0; r < 4; ++r)
                lred[w * 64 + mt * 16 + quad * 4 + r] = lacc[mt][r];
    }
    const int qloc = tid >> 4, dk4 = (tid & 15) * 4;
#pragma unroll
    for (int mt = 0; mt < 4; ++mt) {
        __syncthreads();   // prev round reads done (mt=0: last PV reads done)
#pragma unroll
        for (int nt = 0; nt < 4; ++nt)
#pragma unroll
            for (int r = 0; r < 4; ++r)
                Ored[(w * 16 + quad * 4 + r) * 68 + nt * 16 + l15] = oacc[mt][nt][r];
        __syncthreads();
        f32x4 s = *(const f32x4*)&Ored[(0 * 16 + qloc) * 68 + dk4];
#pragma unroll
        for (int ww = 1; ww < 4; ++ww) {
            f32x4 v = *(const f32x4*)&Ored[(ww * 16 + qloc) * 68 + dk4];
            s += v;
        }
        float l = lred[mt * 16 + qloc] + lred[64 + mt * 16 + qloc]
                + lred[128 + mt * 16 + qloc] + lred[192 + mt * 16 + qloc];
        float inv = 1.0f / l;
        us4 pk;
#pragma unroll
        for (int j = 0; j < 4; ++j) pk[j] = (short)f2bf(s[j] * inv);
        *(us4*)&at_bf[(size_t)(q0 + mt * 16 + qloc) * D_DIM + hoff + dk4] = pk;
    }
}

// ---------------------------------------------------------------------------
// ff2 split-K combine: out = x2 + b2[col] + p0 + p1 (fp32)
// ---------------------------------------------------------------------------
__global__ __launch_bounds__(256) void ff2_combine(
    const float* __restrict__ x2, const float* __restrict__ b2,
    const float* __restrict__ p0, const float* __restrict__ p1,
    float* __restrict__ out)
{
    size_t i = ((size_t)blockIdx.x * 256 + threadIdx.x) * 4;
    f32x4 a  = *(const f32x4*)(x2 + i);
    f32x4 q0 = *(const f32x4*)(p0 + i);
    f32x4 q1 = *(const f32x4*)(p1 + i);
    f32x4 bb = *(const f32x4*)(b2 + (int)(i & 511));
    f32x4 r = a + q0 + q1 + bb;
    *(f32x4*)(out + i) = r;
}

// ---------------------------------------------------------------------------
extern "C" void kernel_launch(void* const* d_in, const int* in_sizes, int n_in,
                              void* d_out, int out_size, void* d_ws, size_t ws_size,
                              hipStream_t stream) {
    (void)in_sizes; (void)n_in; (void)out_size; (void)ws_size;
    const float* x    = (const float*)d_in[0];
    const int*   mask = (const int*)d_in[1];
    const float* wq = (const float*)d_in[2];
    const float* bq = (const float*)d_in[3];
    const float* wk = (const float*)d_in[4];
    const float* bk = (const float*)d_in[5];
    const float* wv = (const float*)d_in[6];
    const float* bv = (const float*)d_in[7];
    const float* wo = (const float*)d_in[8];
    const float* bo = (const float*)d_in[9];
    const float* w1 = (const float*)d_in[10];
    const float* b1 = (const float*)d_in[11];
    const float* w2 = (const float*)d_in[12];
    const float* b2 = (const float*)d_in[13];
    const float* ln1a = (const float*)d_in[14];
    const float* ln1b = (const float*)d_in[15];
    const float* ln2a = (const float*)d_in[16];
    const float* ln2b = (const float*)d_in[17];
    float* out = (float*)d_out;

    const size_t SD = (size_t)S_LEN * D_DIM;
    char* p = (char*)d_ws;
    ushort* wqkvt = (ushort*)p; p += (size_t)1536 * 512 * 2;
    ushort* wot   = (ushort*)p; p += (size_t)512 * 512 * 2;
    ushort* w1t   = (ushort*)p; p += (size_t)2048 * 512 * 2;
    ushort* w2t   = (ushort*)p; p += (size_t)512 * 2048 * 2;
    float*  bqkv  = (float*)p;  p += 1536 * 4;
    float*  mbias = (float*)p;  p += 4096 * 4;
    ushort* h_bf  = (ushort*)p; p += SD * 2;
    ushort* qkv   = (ushort*)p; p += (size_t)4096 * 1536 * 2;
    ushort* vbt   = (ushort*)p; p += SD * 2;
    ushort* at_bf = (ushort*)p; p += SD * 2;
    float*  x2    = (float*)p;  p += SD * 4;
    ushort* h2    = (ushort*)p; p += SD * 2;
    ushort* ff1   = (ushort*)p; p += (size_t)4096 * 2048 * 2;
    float* wopart  = (float*)h_bf;    // wo partials: 2 x SD fp32 (h_bf+qkv region)
    float* ff2part = (float*)h_bf;    // ff2 partials: 2 x SD fp32

    dim3 blk(256);

    prep_all<<<dim3(3088), blk, 0, stream>>>(wq, wk, wv, wo, w1, w2, bq, bk, bv,
                                             mask, wqkvt, wot, w1t, w2t, bqkv, mbias);

    ln1_kernel<<<dim3(S_LEN), blk, 0, stream>>>(x, ln1a, ln1b, h_bf);

    // fused QKV projection (V written transposed to vbt)
    gemm_mfma<<<dim3(24, 32, 1), blk, 0, stream>>>(
        h_bf, wqkvt, bqkv, nullptr, qkv, vbt, S_LEN, 1536, 512, 0, 512);

    // flash attention v3: 1D grid, head = bid&7 (XCD-local K/V)
    flash_mfma<<<dim3(512), blk, 0, stream>>>(qkv, vbt, mbias, at_bf);

    // output projection, split-K x2 -> partials
    gemm_mfma<<<dim3(8, 32, 2), blk, 0, stream>>>(
        at_bf, wot, nullptr, wopart, nullptr, nullptr, S_LEN, 512, 512, 0, 256);

    // x2 = x + bo + partials ; h2 = LN(x2)
    ln2_fused<<<dim3(S_LEN), blk, 0, stream>>>(x, bo, wopart, wopart + SD,
                                               ln2a, ln2b, x2, h2);

    // FFN-1 (relu)
    gemm_mfma<<<dim3(32, 32, 1), blk, 0, stream>>>(
        h2, w1t, b1, nullptr, ff1, nullptr, S_LEN, 2048, 512, 1, 512);

    // FFN-2 split-K x2 -> partials
    gemm_mfma<<<dim3(8, 32, 2), blk, 0, stream>>>(
        ff1, w2t, nullptr, ff2part, nullptr, nullptr, S_LEN, 512, 2048, 0, 1024);

    // out = x2 + b2 + p0 + p1
    ff2_combine<<<dim3(2048), blk, 0, stream>>>(
        x2, b2, ff2part, ff2part + SD, out);
}